// Round 7
// baseline (569.111 us; speedup 1.0000x reference)
//
#include <hip/hip_runtime.h>
#include <math.h>

#define HWc 16384
#define Wd 128
#define Hd 128

typedef __attribute__((ext_vector_type(8))) _Float16 half8;
typedef __attribute__((ext_vector_type(4))) _Float16 half4;
typedef __attribute__((ext_vector_type(4))) float f32x4;

// global(16B) -> LDS DMA; lds base must be wave-uniform.
#define GLDS16(gp, lp) __builtin_amdgcn_global_load_lds( \
    (const __attribute__((address_space(1))) void*)(gp), \
    (__attribute__((address_space(3))) void*)(lp), 16, 0, 0)

// ---------------------------------------------------------------------------
// Weight fragment prep: OIHW fp32 -> f16 fragments, all three weights in one
// launch. Layout per tensor: [t(9)][kc(cin/32)][ot(4)][lane(64)][j(8)]
// (inner math verbatim from proven prep_wfrag_kernel; disjoint outputs)
// ---------------------------------------------------------------------------
__global__ void prep_all_kernel(const float* __restrict__ w_in,
                                const float* __restrict__ w_out,
                                const float* __restrict__ w_comb,
                                _Float16* __restrict__ wf_in,
                                _Float16* __restrict__ wf_out,
                                _Float16* __restrict__ wf_comb)
{
    int bid = blockIdx.x;
    const float* w; _Float16* wf; int cin; int idx;
    if (bid < 144)      { w = w_in;   wf = wf_in;   cin = 64;  idx = bid * 256 + threadIdx.x; }
    else if (bid < 288) { w = w_out;  wf = wf_out;  cin = 64;  idx = (bid - 144) * 256 + threadIdx.x; }
    else                { w = w_comb; wf = wf_comb; cin = 128; idx = (bid - 288) * 256 + threadIdx.x; }
    int total = cin * 576;
    if (idx >= total) return;
    int KC = cin >> 5;
    int j = idx & 7;
    int lane = (idx >> 3) & 63;
    int rest = idx >> 9;
    int ot = rest & 3;
    int rest2 = rest >> 2;
    int kc = rest2 % KC;
    int t = rest2 / KC;
    int oc = ot * 16 + (lane & 15);
    int ci = kc * 32 + ((lane >> 4) << 3) + j;
    wf[idx] = (_Float16)w[((size_t)oc * cin + ci) * 9 + t];
}

// ---------------------------------------------------------------------------
// NCHW fp32 -> pack8 f16:  out[((b*8+g)*HW + p)*8 + k] = in[b, g*8+k, p]
// ---------------------------------------------------------------------------
__global__ __launch_bounds__(256) void pack8_kernel(const float* __restrict__ in,
                                                    _Float16* __restrict__ outp)
{
    int idx = blockIdx.x * 256 + threadIdx.x;
    int b = idx >> 14, p = idx & 16383;
    #pragma unroll
    for (int g = 0; g < 8; g++) {
        half8 v;
        #pragma unroll
        for (int k = 0; k < 8; k++)
            v[k] = (_Float16)in[((size_t)b * 64 + g * 8 + k) * HWc + p];
        *(half8*)&outp[(((size_t)b * 8 + g) * HWc + p) * 8] = v;
    }
}

// ---------------------------------------------------------------------------
// MFMA conv 64->64 3x3 (+BN+ReLU). ONE-WAVE blocks, 4x16 output tile.
// Input slab 6x18x8groups staged via global_load_lds DMA (13.8 KB LDS ->
// 11 blocks/CU). launch_bounds(64,3): VGPR cap ~170 (was 128 — compiler was
// clipped; LDS still binds occupancy at 11 blocks/CU so the headroom is free
// ILP for pipelining the 72 af weight loads). DMAs issued before BN-const
// loads so they drain earliest. All staged values, MFMA order (t outer, kc
// inner), epilogue expressions verbatim -> bit-identical output.
// ---------------------------------------------------------------------------
__global__ __launch_bounds__(64, 3) void mfma_conv64_kernel(
    const _Float16* __restrict__ inp8, const _Float16* __restrict__ wf,
    const float* __restrict__ bng, const float* __restrict__ bnb,
    const float* __restrict__ bnm, const float* __restrict__ bnv,
    _Float16* __restrict__ outp8, float* __restrict__ out32)
{
    __shared__ __align__(16) _Float16 slds[6912];  // [g(8)][y(6)][x(18)][8]
    __shared__ float sc[64], sh[64];
    int lane = threadIdx.x;
    int b = blockIdx.y;
    int tileid = blockIdx.x;          // ty 0..31 (4-row bands), tx 0..7
    int ty = tileid >> 3, tx = tileid & 7;
    int h0 = ty * 4 - 1, w0 = tx * 16 - 1;
    const _Float16* ib = inp8 + (size_t)b * 8 * HWc * 8;
    bool interior = (ty >= 1 && ty <= 30 && tx >= 1 && tx <= 6);
    if (interior) {
        #pragma unroll
        for (int it = 0; it < 14; it++) {
            int i = it * 64 + lane;
            if (i < 864) {
                int g = i / 108;
                int rem = i - g * 108;
                int y = rem / 18, x = rem - (rem / 18) * 18;
                int p = (h0 + y) * Wd + (w0 + x);
                GLDS16(&ib[((size_t)g * HWc + p) * 8], &slds[it * 512]);
            }
        }
    } else {
        // issue in-bounds DMAs; zero-fill OOB slots (disjoint addresses)
        #pragma unroll
        for (int it = 0; it < 14; it++) {
            int i = it * 64 + lane;
            if (i < 864) {
                int g = i / 108;
                int rem = i - g * 108;
                int y = rem / 18, x = rem - (rem / 18) * 18;
                int hh = h0 + y, ww = w0 + x;
                if (hh >= 0 && hh < Hd && ww >= 0 && ww < Wd) {
                    int p = hh * Wd + ww;
                    GLDS16(&ib[((size_t)g * HWc + p) * 8], &slds[it * 512]);
                } else {
                    half8 hz;
                    #pragma unroll
                    for (int k = 0; k < 8; k++) hz[k] = (_Float16)0.f;
                    *(half8*)&slds[i * 8] = hz;
                }
            }
        }
    }
    {   // BN consts after DMA issue (overlaps DMA latency)
        float inv = rsqrtf(bnv[lane] + 1e-5f);
        float s = bng[lane] * inv;
        sc[lane] = s;
        sh[lane] = bnb[lane] - bnm[lane] * s;
    }
    __syncthreads();   // drains DMA (vmcnt) + ds writes; single-wave: cheap
    int lq = lane >> 4, ln = lane & 15;
    f32x4 acc[4][4];
    #pragma unroll
    for (int r = 0; r < 4; r++)
        #pragma unroll
        for (int ot = 0; ot < 4; ot++)
            #pragma unroll
            for (int q = 0; q < 4; q++) acc[r][ot][q] = 0.f;

    for (int t = 0; t < 9; t++) {
        int dy = t / 3, dx = t - (t / 3) * 3;
        #pragma unroll
        for (int kc = 0; kc < 2; kc++) {
            half8 bf[4];
            #pragma unroll
            for (int r = 0; r < 4; r++) {
                int off = (((kc * 4 + lq) * 108) + (r + dy) * 18 + (ln + dx)) * 8;
                bf[r] = *(const half8*)&slds[off];
            }
            #pragma unroll
            for (int ot = 0; ot < 4; ot++) {
                half8 af = *(const half8*)(wf + (size_t)(((t * 2 + kc) * 4 + ot) * 64 + lane) * 8);
                #pragma unroll
                for (int r = 0; r < 4; r++)
                    acc[r][ot] = __builtin_amdgcn_mfma_f32_16x16x32_f16(af, bf[r], acc[r][ot], 0, 0, 0);
            }
        }
    }
    // epilogue: oc = ot*16 + lq*4 + reg = (ot*4+lq)*4 + reg
    #pragma unroll
    for (int r = 0; r < 4; r++) {
        int yy = ty * 4 + r;
        int p = yy * Wd + tx * 16 + ln;
        #pragma unroll
        for (int ot = 0; ot < 4; ot++) {
            int g4 = ot * 4 + lq;
            if (out32) {
                #pragma unroll
                for (int reg = 0; reg < 4; reg++) {
                    int oc = g4 * 4 + reg;
                    float v = fmaf(acc[r][ot][reg], sc[oc], sh[oc]);
                    out32[((size_t)b * 64 + oc) * HWc + p] = fmaxf(v, 0.f);
                }
            } else {
                half4 hv;
                #pragma unroll
                for (int reg = 0; reg < 4; reg++) {
                    int oc = g4 * 4 + reg;
                    float v = fmaf(acc[r][ot][reg], sc[oc], sh[oc]);
                    hv[reg] = (_Float16)fmaxf(v, 0.f);
                }
                *(half4*)&outp8[(((size_t)b * 8 + (g4 >> 1)) * HWc + p) * 8 + (g4 & 1) * 4] = hv;
            }
        }
    }
}

// ---------------------------------------------------------------------------
// MFMA combine conv: cat([fusion1, emod]) (128 ci) -> 64 oc, +bias.
// ONE-WAVE blocks, 4x16 tile, 2 DMA-staged phases (h=0: f1p, h=1: emod).
// launch_bounds(64,3) for af-load pipelining headroom (LDS still binds).
// h-outer / t / kc-inner order preserved -> bit-identical accumulation.
// ---------------------------------------------------------------------------
__global__ __launch_bounds__(64, 3) void mfma_combine_kernel(
    const _Float16* __restrict__ f1p, const _Float16* __restrict__ emod,
    const _Float16* __restrict__ wf, const float* __restrict__ cb,
    _Float16* __restrict__ outp8)
{
    __shared__ __align__(16) _Float16 slds[6912];
    __shared__ float cbl[64];
    int lane = threadIdx.x;
    int b = blockIdx.y;
    int tileid = blockIdx.x;
    int ty = tileid >> 3, tx = tileid & 7;
    int h0 = ty * 4 - 1, w0 = tx * 16 - 1;
    int lq = lane >> 4, ln = lane & 15;
    bool interior = (ty >= 1 && ty <= 30 && tx >= 1 && tx <= 6);
    f32x4 acc[4][4];
    #pragma unroll
    for (int r = 0; r < 4; r++)
        #pragma unroll
        for (int ot = 0; ot < 4; ot++)
            #pragma unroll
            for (int q = 0; q < 4; q++) acc[r][ot][q] = 0.f;

    const _Float16* f1b = f1p + (size_t)b * 8 * HWc * 8;
    const _Float16* emb = emod + (size_t)b * 8 * HWc * 8;
    bool cbl_done = false;
    for (int h = 0; h < 2; h++) {
        const _Float16* src = (h == 0) ? f1b : emb;
        if (h) __syncthreads();  // phase-0 reads done before overwrite
        if (interior) {
            #pragma unroll
            for (int it = 0; it < 14; it++) {
                int i = it * 64 + lane;
                if (i < 864) {
                    int g = i / 108;
                    int rem = i - g * 108;
                    int y = rem / 18, x = rem - (rem / 18) * 18;
                    int p = (h0 + y) * Wd + (w0 + x);
                    GLDS16(&src[((size_t)g * HWc + p) * 8], &slds[it * 512]);
                }
            }
        } else {
            #pragma unroll
            for (int it = 0; it < 14; it++) {
                int i = it * 64 + lane;
                if (i < 864) {
                    int g = i / 108;
                    int rem = i - g * 108;
                    int y = rem / 18, x = rem - (rem / 18) * 18;
                    int hh = h0 + y, ww = w0 + x;
                    if (hh >= 0 && hh < Hd && ww >= 0 && ww < Wd) {
                        int p = hh * Wd + ww;
                        GLDS16(&src[((size_t)g * HWc + p) * 8], &slds[it * 512]);
                    } else {
                        half8 hz;
                        #pragma unroll
                        for (int k = 0; k < 8; k++) hz[k] = (_Float16)0.f;
                        *(half8*)&slds[i * 8] = hz;
                    }
                }
            }
        }
        if (!cbl_done) { cbl[lane] = cb[lane]; cbl_done = true; }  // after DMA issue
        __syncthreads();
        for (int t = 0; t < 9; t++) {
            int dy = t / 3, dx = t - (t / 3) * 3;
            #pragma unroll
            for (int kc = 0; kc < 2; kc++) {
                int kcg = h * 2 + kc;
                half8 bf[4];
                #pragma unroll
                for (int r = 0; r < 4; r++) {
                    int off = (((kc * 4 + lq) * 108) + (r + dy) * 18 + (ln + dx)) * 8;
                    bf[r] = *(const half8*)&slds[off];
                }
                #pragma unroll
                for (int ot = 0; ot < 4; ot++) {
                    half8 af = *(const half8*)(wf + (size_t)(((t * 4 + kcg) * 4 + ot) * 64 + lane) * 8);
                    #pragma unroll
                    for (int r = 0; r < 4; r++)
                        acc[r][ot] = __builtin_amdgcn_mfma_f32_16x16x32_f16(af, bf[r], acc[r][ot], 0, 0, 0);
                }
            }
        }
    }
    #pragma unroll
    for (int r = 0; r < 4; r++) {
        int yy = ty * 4 + r;
        int p = yy * Wd + tx * 16 + ln;
        #pragma unroll
        for (int ot = 0; ot < 4; ot++) {
            int g4 = ot * 4 + lq;
            half4 hv;
            #pragma unroll
            for (int reg = 0; reg < 4; reg++) {
                int oc = g4 * 4 + reg;
                hv[reg] = (_Float16)(acc[r][ot][reg] + cbl[oc]);
            }
            *(half4*)&outp8[(((size_t)b * 8 + (g4 >> 1)) * HWc + p) * 8 + (g4 & 1) * 4] = hv;
        }
    }
}

// ---------------------------------------------------------------------------
// edgemul: emod[c][p] = (f16)( edgeconv(E)[c][p] * ((float)x1[c][p] + 1) )
// ---------------------------------------------------------------------------
__global__ __launch_bounds__(256) void edgemul_kernel(const float* __restrict__ E,
    const _Float16* __restrict__ x1p, const float* __restrict__ edge_w,
    const float* __restrict__ edge_b, _Float16* __restrict__ emod)
{
    __shared__ float ew[576];
    __shared__ float ebl[64];
    int tid = threadIdx.x;
    for (int i = tid; i < 576; i += 256) ew[i] = edge_w[i];
    if (tid < 64) ebl[tid] = edge_b[tid];
    __syncthreads();
    int idx = blockIdx.x * 256 + tid;
    int b = idx >> 14, p = idx & 16383;
    int i = p >> 7, j = p & 127;
    const float* ep = E + (size_t)b * HWc;
    float e[9];
    #pragma unroll
    for (int tt = 0; tt < 9; tt++) {
        int ii = i - 1 + tt / 3, jj = j - 1 + tt % 3;
        e[tt] = (ii >= 0 && ii < Hd && jj >= 0 && jj < Wd) ? ep[ii * Wd + jj] : 0.f;
    }
    const _Float16* xb = x1p + (size_t)b * 8 * HWc * 8;
    _Float16* ob = emod + (size_t)b * 8 * HWc * 8;
    for (int g = 0; g < 8; g++) {
        half8 v = *(const half8*)&xb[((size_t)g * HWc + p) * 8];
        half8 hv;
        #pragma unroll
        for (int k = 0; k < 8; k++) {
            int cc = g * 8 + k;
            float ec = ebl[cc];
            #pragma unroll
            for (int tt = 0; tt < 9; tt++) ec = fmaf(ew[cc * 9 + tt], e[tt], ec);
            float xv = (float)v[k];
            hv[k] = (_Float16)(ec * (xv + 1.0f));
        }
        *(half8*)&ob[((size_t)g * HWc + p) * 8] = hv;
    }
}

// ---------------------------------------------------------------------------
// Scalar 3x3 conv + BN + ReLU, tiny cin (up_w conv, cin=2). Output pack8 f16.
// ---------------------------------------------------------------------------
__global__ __launch_bounds__(256) void conv3x3_bn_kernel(
    const float* __restrict__ in, const float* __restrict__ wgt,
    const float* __restrict__ bng, const float* __restrict__ bnb,
    const float* __restrict__ bnm, const float* __restrict__ bnv,
    _Float16* __restrict__ outp8, int cin)
{
    __shared__ float tile[18*18];
    __shared__ float wl[576];
    __shared__ float sc[64], sh[64];
    int tid = threadIdx.x;
    int tileid = blockIdx.x; int b = blockIdx.y;
    int th = tileid >> 3, tw = tileid & 7;
    int h0 = th*16 - 1, w0 = tw*16 - 1;
    if (tid < 64) {
        float inv = rsqrtf(bnv[tid] + 1e-5f);
        float s = bng[tid]*inv;
        sc[tid] = s;
        sh[tid] = bnb[tid] - bnm[tid]*s;
    }
    float acc[64];
    #pragma unroll
    for (int i=0;i<64;i++) acc[i]=0.f;
    int py = tid>>4, px = tid&15;
    for (int ci=0; ci<cin; ci++){
        __syncthreads();
        const float* inp = in + ((size_t)b*cin + ci)*HWc;
        for (int i = tid; i < 324; i += 256) {
            int y=i/18, x=i%18; int hh=h0+y, ww=w0+x;
            tile[i] = (hh>=0&&hh<Hd&&ww>=0&&ww<Wd) ? inp[hh*Wd+ww] : 0.f;
        }
        for (int i = tid; i < 576; i += 256) {
            int oc = i/9, t = i - oc*9;
            wl[i] = wgt[((size_t)oc*cin + ci)*9 + t];
        }
        __syncthreads();
        float v[9];
        #pragma unroll
        for (int dy=0;dy<3;dy++)
            #pragma unroll
            for (int dx=0;dx<3;dx++)
                v[dy*3+dx] = tile[(py+dy)*18 + px+dx];
        #pragma unroll
        for (int oc=0;oc<64;oc++){
            float a = acc[oc];
            #pragma unroll
            for (int t=0;t<9;t++) a = fmaf(wl[oc*9+t], v[t], a);
            acc[oc]=a;
        }
    }
    int hh = h0+1+py, ww = w0+1+px;
    int p = hh*Wd + ww;
    #pragma unroll
    for (int g=0; g<8; g++){
        half8 hv;
        #pragma unroll
        for (int k=0; k<8; k++){
            int oc = g*8+k;
            float y = fmaf(acc[oc], sc[oc], sh[oc]);
            hv[k] = (_Float16)fmaxf(y, 0.f);
        }
        *(half8*)&outp8[(((size_t)b*8+g)*HWc + p)*8] = hv;
    }
}

// ---------------------------------------------------------------------------
// z maps from pack8 x1: z_t = sum_c down2_w[c,t]*x1[c] (and z1 for down1).
// ---------------------------------------------------------------------------
__global__ __launch_bounds__(256) void zmaps_kernel(const _Float16* __restrict__ x1p,
    const float* __restrict__ w2, const float* __restrict__ w1,
    float* __restrict__ z, float* __restrict__ z1)
{
    int idx = blockIdx.x*256 + threadIdx.x;
    int b = idx >> 14; int p = idx & 16383;
    const _Float16* xb = x1p + (size_t)b*8*HWc*8;
    float a2[9], a1[9];
    #pragma unroll
    for (int t=0;t<9;t++){ a2[t]=0.f; a1[t]=0.f; }
    for (int g=0; g<8; g++){
        half8 v = *(const half8*)&xb[((size_t)g*HWc + p)*8];
        #pragma unroll
        for (int k=0;k<8;k++){
            int c = g*8+k;
            float val = (float)v[k];
            #pragma unroll
            for (int t=0;t<9;t++){
                a2[t] = fmaf(w2[c*9+t], val, a2[t]);
                a1[t] = fmaf(w1[c*9+t], val, a1[t]);
            }
        }
    }
    #pragma unroll
    for (int t=0;t<9;t++){
        z [((size_t)b*9+t)*HWc + p] = a2[t];
        z1[((size_t)b*9+t)*HWc + p] = a1[t];
    }
}

__global__ __launch_bounds__(256) void xin_kernel(const float* __restrict__ z1,
    const float* __restrict__ b1p, float* __restrict__ xin)
{
    int idx = blockIdx.x*256+threadIdx.x;
    int b=idx>>14; int p=idx&16383;
    int i=p>>7, j=p&127;
    float acc = b1p[0];
    #pragma unroll
    for (int t=0;t<9;t++){
        int ii=i+t/3-1, jj=j+t%3-1;
        if (ii>=0&&ii<Hd&&jj>=0&&jj<Wd)
            acc += z1[((size_t)b*9+t)*HWc + ii*Wd+jj];
    }
    xin[idx]=acc;
}

// ---------------------------------------------------------------------------
// Fused upsample+conv -> Haar DWT -> cA, E
// ---------------------------------------------------------------------------
__global__ __launch_bounds__(256) void dwt_kernel(const float* __restrict__ z,
    const float* __restrict__ b2p, float* __restrict__ cA, float* __restrict__ Eo)
{
    int idx = blockIdx.x*256 + threadIdx.x;
    int b = idx >> 14; int p = idx & 16383;
    int u = p >> 7, v = p & 127;
    float b2 = b2p[0];
    int rlo[4], rhi[4]; float rf[4]; bool rv[4];
    int clo[4], chi[4]; float cf[4]; bool cvv[4];
    #pragma unroll
    for (int k=0;k<4;k++){
        int r = 2*u - 1 + k;
        rv[k] = (r>=0 && r<256);
        int rr = rv[k] ? r : 0;
        float cc = ((float)rr * 127.0f) / 255.0f;
        int lo = (int)cc;
        rlo[k]=lo; rhi[k]=min(lo+1,127); rf[k]=cc-(float)lo;
        int s = 2*v - 1 + k;
        cvv[k] = (s>=0 && s<256);
        int ss = cvv[k] ? s : 0;
        float c2 = ((float)ss * 127.0f) / 255.0f;
        int lo2=(int)c2;
        clo[k]=lo2; chi[k]=min(lo2+1,127); cf[k]=c2-(float)lo2;
    }
    float Xin[4] = {b2,b2,b2,b2};
    #pragma unroll
    for (int t=0;t<9;t++){
        int dy=t/3, dx=t%3;
        const float* zp = z + ((size_t)b*9 + t)*HWc;
        #pragma unroll
        for (int e=0;e<4;e++){
            int ey=e>>1, ex=e&1;
            int k=ey+dy, l=ex+dx;
            if (rv[k] && cvv[l]){
                const float* row0 = zp + rlo[k]*Wd;
                const float* row1 = zp + rhi[k]*Wd;
                float v00=row0[clo[l]], v01=row0[chi[l]];
                float v10=row1[clo[l]], v11=row1[chi[l]];
                float fc_=cf[l], fr_=rf[k];
                float top = v00*(1.0f-fc_) + v01*fc_;
                float bot = v10*(1.0f-fc_) + v11*fc_;
                Xin[e] += top*(1.0f-fr_) + bot*fr_;
            }
        }
    }
    float a=Xin[0], bb=Xin[1], c_=Xin[2], d_=Xin[3];
    float LL=0.5f*( a+bb+c_+d_);
    float LH=0.5f*(-a-bb+c_+d_);
    float HL=0.5f*(-a+bb-c_+d_);
    float HH=0.5f*( a-bb-c_+d_);
    cA[(size_t)b*HWc + p] = LL;
    Eo[(size_t)b*HWc + p] = fabsf(LH)+fabsf(HL)+fabsf(HH);
}

__global__ __launch_bounds__(256) void wtgab_kernel(const float* __restrict__ cA,
    const float* __restrict__ xin, const float* __restrict__ wtw, const float* __restrict__ wtb,
    float* __restrict__ wtgab)
{
    __shared__ float gm[49];
    int tid=threadIdx.x;
    if (tid<49){
        int ky=tid/7, kx=tid%7;
        float yy=(float)(ky-3), xx=(float)(kx-3);
        float s=0.f;
        for (int t=0;t<4;t++){
            float theta = (float)t * 0.7853981633974483f;
            float ct=cosf(theta), st=sinf(theta);
            float xt = xx*ct + yy*st;
            float yt = -xx*st + yy*ct;
            s += expf(-0.5f*(xt*xt*(1.0f/16.0f) + yt*yt*(1.0f/64.0f))) * cosf(0.6283185307179586f*xt);
        }
        gm[tid]=0.25f*s;
    }
    __syncthreads();
    int idx = blockIdx.x*256+tid;
    int b=idx>>14; int p=idx&16383;
    int i=p>>7, j=p&127;
    float wacc = wtb[0];
    #pragma unroll
    for (int t=0;t<9;t++){
        int ii=i+t/3-1, jj=j+t%3-1;
        if (ii>=0&&ii<Hd&&jj>=0&&jj<Wd)
            wacc = fmaf(wtw[t], cA[b*HWc + ii*Wd+jj], wacc);
    }
    float g=0.f;
    for (int k=0;k<49;k++){
        int ii=i+k/7-3, jj=j+k%7-3;
        if (ii>=0&&ii<Hd&&jj>=0&&jj<Wd)
            g = fmaf(gm[k], xin[b*HWc + ii*Wd+jj], g);
    }
    wtgab[((size_t)b*2)*HWc + p] = wacc;
    wtgab[((size_t)b*2+1)*HWc + p] = 1.0f/(1.0f+expf(-g));
}

// ---------------------------------------------------------------------------
// CBAM: per-(b,g8) channel pooling from pack8 fusion.
// ---------------------------------------------------------------------------
__global__ __launch_bounds__(256) void pool_kernel(const _Float16* __restrict__ fp8,
    float* __restrict__ pavg, float* __restrict__ pmax)
{
    int b = blockIdx.x >> 3, g = blockIdx.x & 7;
    int tid = threadIdx.x;
    const _Float16* p = fp8 + ((size_t)b*8 + g)*HWc*8;
    float s[8] = {0,0,0,0,0,0,0,0};
    float m[8] = {-3.4e38f,-3.4e38f,-3.4e38f,-3.4e38f,-3.4e38f,-3.4e38f,-3.4e38f,-3.4e38f};
    for (int i=tid;i<HWc;i+=256){
        half8 v = *(const half8*)&p[(size_t)i*8];
        #pragma unroll
        for (int k=0;k<8;k++){ float u=(float)v[k]; s[k]+=u; m[k]=fmaxf(m[k],u); }
    }
    __shared__ float ss[8][256], sm[8][256];
    #pragma unroll
    for (int k=0;k<8;k++){ ss[k][tid]=s[k]; sm[k][tid]=m[k]; }
    __syncthreads();
    for (int st=128; st>0; st>>=1){
        if (tid<st){
            #pragma unroll
            for (int k=0;k<8;k++){
                ss[k][tid]+=ss[k][tid+st];
                sm[k][tid]=fmaxf(sm[k][tid],sm[k][tid+st]);
            }
        }
        __syncthreads();
    }
    if (tid<8){
        pavg[b*64 + g*8 + tid] = ss[tid][0]*(1.0f/16384.0f);
        pmax[b*64 + g*8 + tid] = sm[tid][0];
    }
}

__global__ void mlp_kernel(const float* __restrict__ pavg, const float* __restrict__ pmax,
    const float* __restrict__ fc1, const float* __restrict__ fc2, float* __restrict__ ca)
{
    int b = blockIdx.x; int tid = threadIdx.x; // 64 threads
    __shared__ float hs[4];
    if (tid < 4){
        float sa_=0.f, sm_=0.f;
        for (int c=0;c<64;c++){
            float w = fc1[tid*64+c];
            sa_ = fmaf(w, pavg[b*64+c], sa_);
            sm_ = fmaf(w, pmax[b*64+c], sm_);
        }
        hs[tid] = fmaxf(sa_,0.f) + fmaxf(sm_,0.f);
    }
    __syncthreads();
    float o = 0.f;
    #pragma unroll
    for (int j=0;j<4;j++) o = fmaf(fc2[tid*4+j], hs[j], o);
    ca[b*64+tid] = 1.0f/(1.0f+expf(-o));
}

// spatial stats of fusion*ca (read-only; fusion not modified)
__global__ __launch_bounds__(256) void spstats_kernel(const _Float16* __restrict__ fp8,
    const float* __restrict__ ca, float* __restrict__ spmean, float* __restrict__ spmax)
{
    int idx = blockIdx.x*256+threadIdx.x;
    int b = idx>>14; int p = idx&16383;
    const _Float16* fb = fp8 + (size_t)b*8*HWc*8;
    const float* cp = ca + b*64;
    float s=0.f, m=-3.4e38f;
    for (int g=0; g<8; g++){
        half8 v = *(const half8*)&fb[((size_t)g*HWc + p)*8];
        #pragma unroll
        for (int k=0;k<8;k++){
            float u = (float)v[k] * cp[g*8+k];
            s += u; m = fmaxf(m, u);
        }
    }
    spmean[idx] = s*(1.0f/64.0f);
    spmax[idx] = m;
}

// ---------------------------------------------------------------------------
// spconv + modmul fused: sa computed in-register (verbatim expression), then
// fmod[c][p] = (f16)((float)fusion[c][p] * ca[b][c] * sa) (verbatim modmul).
// ---------------------------------------------------------------------------
__global__ __launch_bounds__(256) void spconv_modmul_kernel(
    const float* __restrict__ spmean, const float* __restrict__ spmax,
    const float* __restrict__ spw, const _Float16* __restrict__ fp8,
    const float* __restrict__ ca, _Float16* __restrict__ outm)
{
    int idx = blockIdx.x*256+threadIdx.x;
    int b=idx>>14; int p=idx&16383;
    int i=p>>7, j=p&127;
    float acc=0.f;
    for (int k=0;k<49;k++){
        int ky=k/7-3, kx=k%7-3;
        int ii=i+ky, jj=j+kx;
        if (ii>=0&&ii<Hd&&jj>=0&&jj<Wd){
            int q = b*HWc + ii*Wd+jj;
            acc = fmaf(spw[k],    spmean[q], acc);
            acc = fmaf(spw[49+k], spmax[q], acc);
        }
    }
    float m = 1.0f/(1.0f+expf(-acc));
    const float* cp = ca + b * 64;
    const _Float16* fb = fp8 + (size_t)b * 8 * HWc * 8;
    _Float16* ob = outm + (size_t)b * 8 * HWc * 8;
    for (int g = 0; g < 8; g++) {
        half8 v = *(const half8*)&fb[((size_t)g * HWc + p) * 8];
        half8 hv;
        #pragma unroll
        for (int k = 0; k < 8; k++)
            hv[k] = (_Float16)((float)v[k] * cp[g * 8 + k] * m);
        *(half8*)&ob[((size_t)g * HWc + p) * 8] = hv;
    }
}

// ---------------------------------------------------------------------------
extern "C" void kernel_launch(void* const* d_in, const int* in_sizes, int n_in,
                              void* d_out, int out_size, void* d_ws, size_t ws_size,
                              hipStream_t stream)
{
    const float* x         = (const float*)d_in[0];
    const float* conv_in_w = (const float*)d_in[1];
    const float* bn1_g = (const float*)d_in[2];
    const float* bn1_b = (const float*)d_in[3];
    const float* bn1_m = (const float*)d_in[4];
    const float* bn1_v = (const float*)d_in[5];
    const float* down1_w = (const float*)d_in[6];
    const float* down1_b = (const float*)d_in[7];
    const float* down2_w = (const float*)d_in[8];
    const float* down2_b = (const float*)d_in[9];
    const float* wt_w = (const float*)d_in[10];
    const float* wt_b = (const float*)d_in[11];
    const float* edge_w = (const float*)d_in[12];
    const float* edge_b = (const float*)d_in[13];
    const float* up_w = (const float*)d_in[14];
    const float* bn2_g = (const float*)d_in[15];
    const float* bn2_b = (const float*)d_in[16];
    const float* bn2_m = (const float*)d_in[17];
    const float* bn2_v = (const float*)d_in[18];
    const float* combine_w = (const float*)d_in[19];
    const float* combine_b = (const float*)d_in[20];
    const float* fc1 = (const float*)d_in[21];
    const float* fc2 = (const float*)d_in[22];
    const float* spw = (const float*)d_in[23];
    const float* out_w = (const float*)d_in[24];
    const float* bn3_g = (const float*)d_in[25];
    const float* bn3_b = (const float*)d_in[26];
    const float* bn3_m = (const float*)d_in[27];
    const float* bn3_v = (const float*)d_in[28];
    float* out = (float*)d_out;
    float* ws = (float*)d_ws;

    // fp32 scratch
    float* z       = ws;                   // 2359296
    float* z1      = z + 2359296;
    float* xin     = z1 + 2359296;         // 262144
    float* cA      = xin + 262144;
    float* Ebuf    = cA + 262144;
    float* wtgab   = Ebuf + 262144;        // 524288
    float* spmean  = wtgab + 524288;
    float* spmaxb  = spmean + 262144;
    float* sabuf   = spmaxb + 262144;      // (unused; kept for layout)
    float* pavg    = sabuf + 262144;       // 1024
    float* pmaxb   = pavg + 1024;
    float* cab     = pmaxb + 1024;
    // f16 pack8 tensors (each 16*8*16384*8 = 16777216 f16)
    _Float16* xp      = (_Float16*)(cab + 1024);
    _Float16* x1p     = xp + 16777216;
    _Float16* f1p     = x1p + 16777216;
    _Float16* fp      = f1p + 16777216;
    // f16 weight fragments
    _Float16* wf_in   = fp + 16777216;     // 36864
    _Float16* wf_out  = wf_in + 36864;
    _Float16* wf_comb = wf_out + 36864;    // 73728
    // buffer reuse: emod overlays xp (dead after first conv64);
    //               fmod overlays f1p (dead after combine).
    _Float16* emod = xp;
    _Float16* fmod = f1p;

    prep_all_kernel<<<576, 256, 0, stream>>>(conv_in_w, out_w, combine_w,
                                             wf_in, wf_out, wf_comb);
    pack8_kernel<<<1024, 256, 0, stream>>>(x, xp);

    dim3 cgrid(256, 16);   // 4x16 tiles, 1-wave blocks
    // x1 = relu(bn1(conv_in(x)))
    mfma_conv64_kernel<<<cgrid, 64, 0, stream>>>(xp, wf_in, bn1_g,bn1_b,bn1_m,bn1_v,
                                                 x1p, nullptr);
    zmaps_kernel<<<1024, 256, 0, stream>>>(x1p, down2_w, down1_w, z, z1);
    xin_kernel<<<1024, 256, 0, stream>>>(z1, down1_b, xin);
    dwt_kernel<<<1024, 256, 0, stream>>>(z, down2_b, cA, Ebuf);
    wtgab_kernel<<<1024, 256, 0, stream>>>(cA, xin, wt_w, wt_b, wtgab);
    conv3x3_bn_kernel<<<dim3(64,16), 256, 0, stream>>>(wtgab, up_w, bn2_g,bn2_b,bn2_m,bn2_v, f1p, 2);
    // edge*(x1+1) precompute (xp is dead -> emod)
    edgemul_kernel<<<1024, 256, 0, stream>>>(Ebuf, x1p, edge_w, edge_b, emod);
    mfma_combine_kernel<<<cgrid, 64, 0, stream>>>(f1p, emod, wf_comb, combine_b, fp);
    pool_kernel<<<128, 256, 0, stream>>>(fp, pavg, pmaxb);
    mlp_kernel<<<16, 64, 0, stream>>>(pavg, pmaxb, fc1, fc2, cab);
    spstats_kernel<<<1024, 256, 0, stream>>>(fp, cab, spmean, spmaxb);
    // spatial-attn conv + fusion*ca*sa in one pass (f1p is dead -> fmod)
    spconv_modmul_kernel<<<1024, 256, 0, stream>>>(spmean, spmaxb, spw, fp, cab, fmod);
    // out = relu(bn3(conv(fmod, out_w)))
    mfma_conv64_kernel<<<cgrid, 64, 0, stream>>>(fmod, wf_out, bn3_g,bn3_b,bn3_m,bn3_v,
                                                 nullptr, out);
}

// Round 8
// 564.256 us; speedup vs baseline: 1.0086x; 1.0086x over previous
//
#include <hip/hip_runtime.h>
#include <math.h>

#define HWc 16384
#define Wd 128
#define Hd 128

typedef __attribute__((ext_vector_type(8))) _Float16 half8;
typedef __attribute__((ext_vector_type(4))) _Float16 half4;
typedef __attribute__((ext_vector_type(4))) float f32x4;

// global(16B) -> LDS DMA; lds base must be wave-uniform.
#define GLDS16(gp, lp) __builtin_amdgcn_global_load_lds( \
    (const __attribute__((address_space(1))) void*)(gp), \
    (__attribute__((address_space(3))) void*)(lp), 16, 0, 0)

// ---------------------------------------------------------------------------
// Weight fragment prep: OIHW fp32 -> f16 fragments, all three weights in one
// launch. Layout per tensor: [t(9)][kc(cin/32)][ot(4)][lane(64)][j(8)]
// ---------------------------------------------------------------------------
__global__ void prep_all_kernel(const float* __restrict__ w_in,
                                const float* __restrict__ w_out,
                                const float* __restrict__ w_comb,
                                _Float16* __restrict__ wf_in,
                                _Float16* __restrict__ wf_out,
                                _Float16* __restrict__ wf_comb)
{
    int bid = blockIdx.x;
    const float* w; _Float16* wf; int cin; int idx;
    if (bid < 144)      { w = w_in;   wf = wf_in;   cin = 64;  idx = bid * 256 + threadIdx.x; }
    else if (bid < 288) { w = w_out;  wf = wf_out;  cin = 64;  idx = (bid - 144) * 256 + threadIdx.x; }
    else                { w = w_comb; wf = wf_comb; cin = 128; idx = (bid - 288) * 256 + threadIdx.x; }
    int total = cin * 576;
    if (idx >= total) return;
    int KC = cin >> 5;
    int j = idx & 7;
    int lane = (idx >> 3) & 63;
    int rest = idx >> 9;
    int ot = rest & 3;
    int rest2 = rest >> 2;
    int kc = rest2 % KC;
    int t = rest2 / KC;
    int oc = ot * 16 + (lane & 15);
    int ci = kc * 32 + ((lane >> 4) << 3) + j;
    wf[idx] = (_Float16)w[((size_t)oc * cin + ci) * 9 + t];
}

// ---------------------------------------------------------------------------
// NCHW fp32 -> pack8 f16:  out[((b*8+g)*HW + p)*8 + k] = in[b, g*8+k, p]
// ---------------------------------------------------------------------------
__global__ __launch_bounds__(256) void pack8_kernel(const float* __restrict__ in,
                                                    _Float16* __restrict__ outp)
{
    int idx = blockIdx.x * 256 + threadIdx.x;
    int b = idx >> 14, p = idx & 16383;
    #pragma unroll
    for (int g = 0; g < 8; g++) {
        half8 v;
        #pragma unroll
        for (int k = 0; k < 8; k++)
            v[k] = (_Float16)in[((size_t)b * 64 + g * 8 + k) * HWc + p];
        *(half8*)&outp[(((size_t)b * 8 + g) * HWc + p) * 8] = v;
    }
}

// ---------------------------------------------------------------------------
// MFMA conv 64->64 3x3 (+BN+ReLU). ONE-WAVE blocks, 4x16 output tile.
// Input slab 6x18x8groups staged via global_load_lds DMA (13.8 KB LDS ->
// 11 blocks/CU). launch_bounds(64,4): VGPR cap 128 — proven no-spill point
// (R7's (64,3) spilled the whole accumulator: +64MB scratch writes).
// NEW vs R6: explicit one-iteration rolling prefetch of the 4 af weight
// fragments (identical addresses/values/MFMA order -> bit-identical output;
// hides ~200cy L2 latency of af loads under the previous iteration's MFMAs).
// ---------------------------------------------------------------------------
__global__ __launch_bounds__(64, 4) void mfma_conv64_kernel(
    const _Float16* __restrict__ inp8, const _Float16* __restrict__ wf,
    const float* __restrict__ bng, const float* __restrict__ bnb,
    const float* __restrict__ bnm, const float* __restrict__ bnv,
    _Float16* __restrict__ outp8, float* __restrict__ out32)
{
    __shared__ __align__(16) _Float16 slds[6912];  // [g(8)][y(6)][x(18)][8]
    __shared__ float sc[64], sh[64];
    int lane = threadIdx.x;
    int b = blockIdx.y;
    int tileid = blockIdx.x;          // ty 0..31 (4-row bands), tx 0..7
    int ty = tileid >> 3, tx = tileid & 7;
    int h0 = ty * 4 - 1, w0 = tx * 16 - 1;
    {
        float inv = rsqrtf(bnv[lane] + 1e-5f);
        float s = bng[lane] * inv;
        sc[lane] = s;
        sh[lane] = bnb[lane] - bnm[lane] * s;
    }
    const _Float16* ib = inp8 + (size_t)b * 8 * HWc * 8;
    bool interior = (ty >= 1 && ty <= 30 && tx >= 1 && tx <= 6);
    if (interior) {
        #pragma unroll
        for (int it = 0; it < 14; it++) {
            int i = it * 64 + lane;
            if (i < 864) {
                int g = i / 108;
                int rem = i - g * 108;
                int y = rem / 18, x = rem - (rem / 18) * 18;
                int p = (h0 + y) * Wd + (w0 + x);
                GLDS16(&ib[((size_t)g * HWc + p) * 8], &slds[it * 512]);
            }
        }
    } else {
        // issue in-bounds DMAs; zero-fill OOB slots (disjoint addresses)
        #pragma unroll
        for (int it = 0; it < 14; it++) {
            int i = it * 64 + lane;
            if (i < 864) {
                int g = i / 108;
                int rem = i - g * 108;
                int y = rem / 18, x = rem - (rem / 18) * 18;
                int hh = h0 + y, ww = w0 + x;
                if (hh >= 0 && hh < Hd && ww >= 0 && ww < Wd) {
                    int p = hh * Wd + ww;
                    GLDS16(&ib[((size_t)g * HWc + p) * 8], &slds[it * 512]);
                } else {
                    half8 hz;
                    #pragma unroll
                    for (int k = 0; k < 8; k++) hz[k] = (_Float16)0.f;
                    *(half8*)&slds[i * 8] = hz;
                }
            }
        }
    }
    __syncthreads();   // drains DMA (vmcnt) + ds writes; single-wave: cheap
    int lq = lane >> 4, ln = lane & 15;
    f32x4 acc[4][4];
    #pragma unroll
    for (int r = 0; r < 4; r++)
        #pragma unroll
        for (int ot = 0; ot < 4; ot++)
            #pragma unroll
            for (int q = 0; q < 4; q++) acc[r][ot][q] = 0.f;

    // rolling af prefetch: it = t*2+kc, wf index (((it)*4+ot)*64+lane)*8
    half8 afp[4];
    #pragma unroll
    for (int ot = 0; ot < 4; ot++)
        afp[ot] = *(const half8*)(wf + (size_t)((0 * 4 + ot) * 64 + lane) * 8);
    #pragma unroll
    for (int it = 0; it < 18; it++) {
        int t = it >> 1, kc = it & 1;
        int dy = t / 3, dx = t - (t / 3) * 3;
        half8 afc[4];
        #pragma unroll
        for (int ot = 0; ot < 4; ot++) afc[ot] = afp[ot];
        if (it < 17) {
            #pragma unroll
            for (int ot = 0; ot < 4; ot++)
                afp[ot] = *(const half8*)(wf + (size_t)(((it + 1) * 4 + ot) * 64 + lane) * 8);
        }
        half8 bf[4];
        #pragma unroll
        for (int r = 0; r < 4; r++) {
            int off = (((kc * 4 + lq) * 108) + (r + dy) * 18 + (ln + dx)) * 8;
            bf[r] = *(const half8*)&slds[off];
        }
        #pragma unroll
        for (int ot = 0; ot < 4; ot++) {
            #pragma unroll
            for (int r = 0; r < 4; r++)
                acc[r][ot] = __builtin_amdgcn_mfma_f32_16x16x32_f16(afc[ot], bf[r], acc[r][ot], 0, 0, 0);
        }
    }
    // epilogue: oc = ot*16 + lq*4 + reg = (ot*4+lq)*4 + reg
    #pragma unroll
    for (int r = 0; r < 4; r++) {
        int yy = ty * 4 + r;
        int p = yy * Wd + tx * 16 + ln;
        #pragma unroll
        for (int ot = 0; ot < 4; ot++) {
            int g4 = ot * 4 + lq;
            if (out32) {
                #pragma unroll
                for (int reg = 0; reg < 4; reg++) {
                    int oc = g4 * 4 + reg;
                    float v = fmaf(acc[r][ot][reg], sc[oc], sh[oc]);
                    out32[((size_t)b * 64 + oc) * HWc + p] = fmaxf(v, 0.f);
                }
            } else {
                half4 hv;
                #pragma unroll
                for (int reg = 0; reg < 4; reg++) {
                    int oc = g4 * 4 + reg;
                    float v = fmaf(acc[r][ot][reg], sc[oc], sh[oc]);
                    hv[reg] = (_Float16)fmaxf(v, 0.f);
                }
                *(half4*)&outp8[(((size_t)b * 8 + (g4 >> 1)) * HWc + p) * 8 + (g4 & 1) * 4] = hv;
            }
        }
    }
}

// ---------------------------------------------------------------------------
// MFMA combine conv: cat([fusion1, emod]) (128 ci) -> 64 oc, +bias.
// ONE-WAVE blocks, 4x16 tile, 2 DMA-staged phases (h=0: f1p, h=1: emod).
// launch_bounds(64,4) (proven no-spill). Rolling af prefetch as in conv64.
// h-outer / t / kc-inner order preserved -> bit-identical accumulation.
// ---------------------------------------------------------------------------
__global__ __launch_bounds__(64, 4) void mfma_combine_kernel(
    const _Float16* __restrict__ f1p, const _Float16* __restrict__ emod,
    const _Float16* __restrict__ wf, const float* __restrict__ cb,
    _Float16* __restrict__ outp8)
{
    __shared__ __align__(16) _Float16 slds[6912];
    __shared__ float cbl[64];
    int lane = threadIdx.x;
    int b = blockIdx.y;
    int tileid = blockIdx.x;
    int ty = tileid >> 3, tx = tileid & 7;
    int h0 = ty * 4 - 1, w0 = tx * 16 - 1;
    cbl[lane] = cb[lane];
    int lq = lane >> 4, ln = lane & 15;
    bool interior = (ty >= 1 && ty <= 30 && tx >= 1 && tx <= 6);
    f32x4 acc[4][4];
    #pragma unroll
    for (int r = 0; r < 4; r++)
        #pragma unroll
        for (int ot = 0; ot < 4; ot++)
            #pragma unroll
            for (int q = 0; q < 4; q++) acc[r][ot][q] = 0.f;

    const _Float16* f1b = f1p + (size_t)b * 8 * HWc * 8;
    const _Float16* emb = emod + (size_t)b * 8 * HWc * 8;
    for (int h = 0; h < 2; h++) {
        const _Float16* src = (h == 0) ? f1b : emb;
        if (h) __syncthreads();  // phase-0 reads done before overwrite
        if (interior) {
            #pragma unroll
            for (int it = 0; it < 14; it++) {
                int i = it * 64 + lane;
                if (i < 864) {
                    int g = i / 108;
                    int rem = i - g * 108;
                    int y = rem / 18, x = rem - (rem / 18) * 18;
                    int p = (h0 + y) * Wd + (w0 + x);
                    GLDS16(&src[((size_t)g * HWc + p) * 8], &slds[it * 512]);
                }
            }
        } else {
            #pragma unroll
            for (int it = 0; it < 14; it++) {
                int i = it * 64 + lane;
                if (i < 864) {
                    int g = i / 108;
                    int rem = i - g * 108;
                    int y = rem / 18, x = rem - (rem / 18) * 18;
                    int hh = h0 + y, ww = w0 + x;
                    if (hh >= 0 && hh < Hd && ww >= 0 && ww < Wd) {
                        int p = hh * Wd + ww;
                        GLDS16(&src[((size_t)g * HWc + p) * 8], &slds[it * 512]);
                    } else {
                        half8 hz;
                        #pragma unroll
                        for (int k = 0; k < 8; k++) hz[k] = (_Float16)0.f;
                        *(half8*)&slds[i * 8] = hz;
                    }
                }
            }
        }
        __syncthreads();
        // rolling af prefetch: within phase h, it = t*2+kc,
        // wf index = ((t*4 + h*2 + kc)*4 + ot)*64*8  (kcg = h*2+kc, verbatim)
        half8 afp[4];
        #pragma unroll
        for (int ot = 0; ot < 4; ot++)
            afp[ot] = *(const half8*)(wf + (size_t)(((0 * 4 + h * 2 + 0) * 4 + ot) * 64 + lane) * 8);
        #pragma unroll
        for (int it = 0; it < 18; it++) {
            int t = it >> 1, kc = it & 1;
            int dy = t / 3, dx = t - (t / 3) * 3;
            half8 afc[4];
            #pragma unroll
            for (int ot = 0; ot < 4; ot++) afc[ot] = afp[ot];
            if (it < 17) {
                int tn = (it + 1) >> 1, kcn = (it + 1) & 1;
                #pragma unroll
                for (int ot = 0; ot < 4; ot++)
                    afp[ot] = *(const half8*)(wf + (size_t)(((tn * 4 + h * 2 + kcn) * 4 + ot) * 64 + lane) * 8);
            }
            half8 bf[4];
            #pragma unroll
            for (int r = 0; r < 4; r++) {
                int off = (((kc * 4 + lq) * 108) + (r + dy) * 18 + (ln + dx)) * 8;
                bf[r] = *(const half8*)&slds[off];
            }
            #pragma unroll
            for (int ot = 0; ot < 4; ot++) {
                #pragma unroll
                for (int r = 0; r < 4; r++)
                    acc[r][ot] = __builtin_amdgcn_mfma_f32_16x16x32_f16(afc[ot], bf[r], acc[r][ot], 0, 0, 0);
            }
        }
    }
    #pragma unroll
    for (int r = 0; r < 4; r++) {
        int yy = ty * 4 + r;
        int p = yy * Wd + tx * 16 + ln;
        #pragma unroll
        for (int ot = 0; ot < 4; ot++) {
            int g4 = ot * 4 + lq;
            half4 hv;
            #pragma unroll
            for (int reg = 0; reg < 4; reg++) {
                int oc = g4 * 4 + reg;
                hv[reg] = (_Float16)(acc[r][ot][reg] + cbl[oc]);
            }
            *(half4*)&outp8[(((size_t)b * 8 + (g4 >> 1)) * HWc + p) * 8 + (g4 & 1) * 4] = hv;
        }
    }
}

// ---------------------------------------------------------------------------
// edgemul: emod[c][p] = (f16)( edgeconv(E)[c][p] * ((float)x1[c][p] + 1) )
// ---------------------------------------------------------------------------
__global__ __launch_bounds__(256) void edgemul_kernel(const float* __restrict__ E,
    const _Float16* __restrict__ x1p, const float* __restrict__ edge_w,
    const float* __restrict__ edge_b, _Float16* __restrict__ emod)
{
    __shared__ float ew[576];
    __shared__ float ebl[64];
    int tid = threadIdx.x;
    for (int i = tid; i < 576; i += 256) ew[i] = edge_w[i];
    if (tid < 64) ebl[tid] = edge_b[tid];
    __syncthreads();
    int idx = blockIdx.x * 256 + tid;
    int b = idx >> 14, p = idx & 16383;
    int i = p >> 7, j = p & 127;
    const float* ep = E + (size_t)b * HWc;
    float e[9];
    #pragma unroll
    for (int tt = 0; tt < 9; tt++) {
        int ii = i - 1 + tt / 3, jj = j - 1 + tt % 3;
        e[tt] = (ii >= 0 && ii < Hd && jj >= 0 && jj < Wd) ? ep[ii * Wd + jj] : 0.f;
    }
    const _Float16* xb = x1p + (size_t)b * 8 * HWc * 8;
    _Float16* ob = emod + (size_t)b * 8 * HWc * 8;
    for (int g = 0; g < 8; g++) {
        half8 v = *(const half8*)&xb[((size_t)g * HWc + p) * 8];
        half8 hv;
        #pragma unroll
        for (int k = 0; k < 8; k++) {
            int cc = g * 8 + k;
            float ec = ebl[cc];
            #pragma unroll
            for (int tt = 0; tt < 9; tt++) ec = fmaf(ew[cc * 9 + tt], e[tt], ec);
            float xv = (float)v[k];
            hv[k] = (_Float16)(ec * (xv + 1.0f));
        }
        *(half8*)&ob[((size_t)g * HWc + p) * 8] = hv;
    }
}

// ---------------------------------------------------------------------------
// Scalar 3x3 conv + BN + ReLU, tiny cin (up_w conv, cin=2). Output pack8 f16.
// ---------------------------------------------------------------------------
__global__ __launch_bounds__(256) void conv3x3_bn_kernel(
    const float* __restrict__ in, const float* __restrict__ wgt,
    const float* __restrict__ bng, const float* __restrict__ bnb,
    const float* __restrict__ bnm, const float* __restrict__ bnv,
    _Float16* __restrict__ outp8, int cin)
{
    __shared__ float tile[18*18];
    __shared__ float wl[576];
    __shared__ float sc[64], sh[64];
    int tid = threadIdx.x;
    int tileid = blockIdx.x; int b = blockIdx.y;
    int th = tileid >> 3, tw = tileid & 7;
    int h0 = th*16 - 1, w0 = tw*16 - 1;
    if (tid < 64) {
        float inv = rsqrtf(bnv[tid] + 1e-5f);
        float s = bng[tid]*inv;
        sc[tid] = s;
        sh[tid] = bnb[tid] - bnm[tid]*s;
    }
    float acc[64];
    #pragma unroll
    for (int i=0;i<64;i++) acc[i]=0.f;
    int py = tid>>4, px = tid&15;
    for (int ci=0; ci<cin; ci++){
        __syncthreads();
        const float* inp = in + ((size_t)b*cin + ci)*HWc;
        for (int i = tid; i < 324; i += 256) {
            int y=i/18, x=i%18; int hh=h0+y, ww=w0+x;
            tile[i] = (hh>=0&&hh<Hd&&ww>=0&&ww<Wd) ? inp[hh*Wd+ww] : 0.f;
        }
        for (int i = tid; i < 576; i += 256) {
            int oc = i/9, t = i - oc*9;
            wl[i] = wgt[((size_t)oc*cin + ci)*9 + t];
        }
        __syncthreads();
        float v[9];
        #pragma unroll
        for (int dy=0;dy<3;dy++)
            #pragma unroll
            for (int dx=0;dx<3;dx++)
                v[dy*3+dx] = tile[(py+dy)*18 + px+dx];
        #pragma unroll
        for (int oc=0;oc<64;oc++){
            float a = acc[oc];
            #pragma unroll
            for (int t=0;t<9;t++) a = fmaf(wl[oc*9+t], v[t], a);
            acc[oc]=a;
        }
    }
    int hh = h0+1+py, ww = w0+1+px;
    int p = hh*Wd + ww;
    #pragma unroll
    for (int g=0; g<8; g++){
        half8 hv;
        #pragma unroll
        for (int k=0; k<8; k++){
            int oc = g*8+k;
            float y = fmaf(acc[oc], sc[oc], sh[oc]);
            hv[k] = (_Float16)fmaxf(y, 0.f);
        }
        *(half8*)&outp8[(((size_t)b*8+g)*HWc + p)*8] = hv;
    }
}

// ---------------------------------------------------------------------------
// z maps from pack8 x1: z_t = sum_c down2_w[c,t]*x1[c] (and z1 for down1).
// ---------------------------------------------------------------------------
__global__ __launch_bounds__(256) void zmaps_kernel(const _Float16* __restrict__ x1p,
    const float* __restrict__ w2, const float* __restrict__ w1,
    float* __restrict__ z, float* __restrict__ z1)
{
    int idx = blockIdx.x*256 + threadIdx.x;
    int b = idx >> 14; int p = idx & 16383;
    const _Float16* xb = x1p + (size_t)b*8*HWc*8;
    float a2[9], a1[9];
    #pragma unroll
    for (int t=0;t<9;t++){ a2[t]=0.f; a1[t]=0.f; }
    for (int g=0; g<8; g++){
        half8 v = *(const half8*)&xb[((size_t)g*HWc + p)*8];
        #pragma unroll
        for (int k=0;k<8;k++){
            int c = g*8+k;
            float val = (float)v[k];
            #pragma unroll
            for (int t=0;t<9;t++){
                a2[t] = fmaf(w2[c*9+t], val, a2[t]);
                a1[t] = fmaf(w1[c*9+t], val, a1[t]);
            }
        }
    }
    #pragma unroll
    for (int t=0;t<9;t++){
        z [((size_t)b*9+t)*HWc + p] = a2[t];
        z1[((size_t)b*9+t)*HWc + p] = a1[t];
    }
}

__global__ __launch_bounds__(256) void xin_kernel(const float* __restrict__ z1,
    const float* __restrict__ b1p, float* __restrict__ xin)
{
    int idx = blockIdx.x*256+threadIdx.x;
    int b=idx>>14; int p=idx&16383;
    int i=p>>7, j=p&127;
    float acc = b1p[0];
    #pragma unroll
    for (int t=0;t<9;t++){
        int ii=i+t/3-1, jj=j+t%3-1;
        if (ii>=0&&ii<Hd&&jj>=0&&jj<Wd)
            acc += z1[((size_t)b*9+t)*HWc + ii*Wd+jj];
    }
    xin[idx]=acc;
}

// ---------------------------------------------------------------------------
// Fused upsample+conv -> Haar DWT -> cA, E
// ---------------------------------------------------------------------------
__global__ __launch_bounds__(256) void dwt_kernel(const float* __restrict__ z,
    const float* __restrict__ b2p, float* __restrict__ cA, float* __restrict__ Eo)
{
    int idx = blockIdx.x*256 + threadIdx.x;
    int b = idx >> 14; int p = idx & 16383;
    int u = p >> 7, v = p & 127;
    float b2 = b2p[0];
    int rlo[4], rhi[4]; float rf[4]; bool rv[4];
    int clo[4], chi[4]; float cf[4]; bool cvv[4];
    #pragma unroll
    for (int k=0;k<4;k++){
        int r = 2*u - 1 + k;
        rv[k] = (r>=0 && r<256);
        int rr = rv[k] ? r : 0;
        float cc = ((float)rr * 127.0f) / 255.0f;
        int lo = (int)cc;
        rlo[k]=lo; rhi[k]=min(lo+1,127); rf[k]=cc-(float)lo;
        int s = 2*v - 1 + k;
        cvv[k] = (s>=0 && s<256);
        int ss = cvv[k] ? s : 0;
        float c2 = ((float)ss * 127.0f) / 255.0f;
        int lo2=(int)c2;
        clo[k]=lo2; chi[k]=min(lo2+1,127); cf[k]=c2-(float)lo2;
    }
    float Xin[4] = {b2,b2,b2,b2};
    #pragma unroll
    for (int t=0;t<9;t++){
        int dy=t/3, dx=t%3;
        const float* zp = z + ((size_t)b*9 + t)*HWc;
        #pragma unroll
        for (int e=0;e<4;e++){
            int ey=e>>1, ex=e&1;
            int k=ey+dy, l=ex+dx;
            if (rv[k] && cvv[l]){
                const float* row0 = zp + rlo[k]*Wd;
                const float* row1 = zp + rhi[k]*Wd;
                float v00=row0[clo[l]], v01=row0[chi[l]];
                float v10=row1[clo[l]], v11=row1[chi[l]];
                float fc_=cf[l], fr_=rf[k];
                float top = v00*(1.0f-fc_) + v01*fc_;
                float bot = v10*(1.0f-fc_) + v11*fc_;
                Xin[e] += top*(1.0f-fr_) + bot*fr_;
            }
        }
    }
    float a=Xin[0], bb=Xin[1], c_=Xin[2], d_=Xin[3];
    float LL=0.5f*( a+bb+c_+d_);
    float LH=0.5f*(-a-bb+c_+d_);
    float HL=0.5f*(-a+bb-c_+d_);
    float HH=0.5f*( a-bb-c_+d_);
    cA[(size_t)b*HWc + p] = LL;
    Eo[(size_t)b*HWc + p] = fabsf(LH)+fabsf(HL)+fabsf(HH);
}

__global__ __launch_bounds__(256) void wtgab_kernel(const float* __restrict__ cA,
    const float* __restrict__ xin, const float* __restrict__ wtw, const float* __restrict__ wtb,
    float* __restrict__ wtgab)
{
    __shared__ float gm[49];
    int tid=threadIdx.x;
    if (tid<49){
        int ky=tid/7, kx=tid%7;
        float yy=(float)(ky-3), xx=(float)(kx-3);
        float s=0.f;
        for (int t=0;t<4;t++){
            float theta = (float)t * 0.7853981633974483f;
            float ct=cosf(theta), st=sinf(theta);
            float xt = xx*ct + yy*st;
            float yt = -xx*st + yy*ct;
            s += expf(-0.5f*(xt*xt*(1.0f/16.0f) + yt*yt*(1.0f/64.0f))) * cosf(0.6283185307179586f*xt);
        }
        gm[tid]=0.25f*s;
    }
    __syncthreads();
    int idx = blockIdx.x*256+tid;
    int b=idx>>14; int p=idx&16383;
    int i=p>>7, j=p&127;
    float wacc = wtb[0];
    #pragma unroll
    for (int t=0;t<9;t++){
        int ii=i+t/3-1, jj=j+t%3-1;
        if (ii>=0&&ii<Hd&&jj>=0&&jj<Wd)
            wacc = fmaf(wtw[t], cA[b*HWc + ii*Wd+jj], wacc);
    }
    float g=0.f;
    for (int k=0;k<49;k++){
        int ii=i+k/7-3, jj=j+k%7-3;
        if (ii>=0&&ii<Hd&&jj>=0&&jj<Wd)
            g = fmaf(gm[k], xin[b*HWc + ii*Wd+jj], g);
    }
    wtgab[((size_t)b*2)*HWc + p] = wacc;
    wtgab[((size_t)b*2+1)*HWc + p] = 1.0f/(1.0f+expf(-g));
}

// ---------------------------------------------------------------------------
// CBAM: per-(b,g8) channel pooling from pack8 fusion.
// ---------------------------------------------------------------------------
__global__ __launch_bounds__(256) void pool_kernel(const _Float16* __restrict__ fp8,
    float* __restrict__ pavg, float* __restrict__ pmax)
{
    int b = blockIdx.x >> 3, g = blockIdx.x & 7;
    int tid = threadIdx.x;
    const _Float16* p = fp8 + ((size_t)b*8 + g)*HWc*8;
    float s[8] = {0,0,0,0,0,0,0,0};
    float m[8] = {-3.4e38f,-3.4e38f,-3.4e38f,-3.4e38f,-3.4e38f,-3.4e38f,-3.4e38f,-3.4e38f};
    for (int i=tid;i<HWc;i+=256){
        half8 v = *(const half8*)&p[(size_t)i*8];
        #pragma unroll
        for (int k=0;k<8;k++){ float u=(float)v[k]; s[k]+=u; m[k]=fmaxf(m[k],u); }
    }
    __shared__ float ss[8][256], sm[8][256];
    #pragma unroll
    for (int k=0;k<8;k++){ ss[k][tid]=s[k]; sm[k][tid]=m[k]; }
    __syncthreads();
    for (int st=128; st>0; st>>=1){
        if (tid<st){
            #pragma unroll
            for (int k=0;k<8;k++){
                ss[k][tid]+=ss[k][tid+st];
                sm[k][tid]=fmaxf(sm[k][tid],sm[k][tid+st]);
            }
        }
        __syncthreads();
    }
    if (tid<8){
        pavg[b*64 + g*8 + tid] = ss[tid][0]*(1.0f/16384.0f);
        pmax[b*64 + g*8 + tid] = sm[tid][0];
    }
}

__global__ void mlp_kernel(const float* __restrict__ pavg, const float* __restrict__ pmax,
    const float* __restrict__ fc1, const float* __restrict__ fc2, float* __restrict__ ca)
{
    int b = blockIdx.x; int tid = threadIdx.x; // 64 threads
    __shared__ float hs[4];
    if (tid < 4){
        float sa_=0.f, sm_=0.f;
        for (int c=0;c<64;c++){
            float w = fc1[tid*64+c];
            sa_ = fmaf(w, pavg[b*64+c], sa_);
            sm_ = fmaf(w, pmax[b*64+c], sm_);
        }
        hs[tid] = fmaxf(sa_,0.f) + fmaxf(sm_,0.f);
    }
    __syncthreads();
    float o = 0.f;
    #pragma unroll
    for (int j=0;j<4;j++) o = fmaf(fc2[tid*4+j], hs[j], o);
    ca[b*64+tid] = 1.0f/(1.0f+expf(-o));
}

// spatial stats of fusion*ca (read-only; fusion not modified)
__global__ __launch_bounds__(256) void spstats_kernel(const _Float16* __restrict__ fp8,
    const float* __restrict__ ca, float* __restrict__ spmean, float* __restrict__ spmax)
{
    int idx = blockIdx.x*256+threadIdx.x;
    int b = idx>>14; int p = idx&16383;
    const _Float16* fb = fp8 + (size_t)b*8*HWc*8;
    const float* cp = ca + b*64;
    float s=0.f, m=-3.4e38f;
    for (int g=0; g<8; g++){
        half8 v = *(const half8*)&fb[((size_t)g*HWc + p)*8];
        #pragma unroll
        for (int k=0;k<8;k++){
            float u = (float)v[k] * cp[g*8+k];
            s += u; m = fmaxf(m, u);
        }
    }
    spmean[idx] = s*(1.0f/64.0f);
    spmax[idx] = m;
}

// ---------------------------------------------------------------------------
// spconv + modmul fused: sa computed in-register (verbatim expression), then
// fmod[c][p] = (f16)((float)fusion[c][p] * ca[b][c] * sa) (verbatim modmul).
// ---------------------------------------------------------------------------
__global__ __launch_bounds__(256) void spconv_modmul_kernel(
    const float* __restrict__ spmean, const float* __restrict__ spmax,
    const float* __restrict__ spw, const _Float16* __restrict__ fp8,
    const float* __restrict__ ca, _Float16* __restrict__ outm)
{
    int idx = blockIdx.x*256+threadIdx.x;
    int b=idx>>14; int p=idx&16383;
    int i=p>>7, j=p&127;
    float acc=0.f;
    for (int k=0;k<49;k++){
        int ky=k/7-3, kx=k%7-3;
        int ii=i+ky, jj=j+kx;
        if (ii>=0&&ii<Hd&&jj>=0&&jj<Wd){
            int q = b*HWc + ii*Wd+jj;
            acc = fmaf(spw[k],    spmean[q], acc);
            acc = fmaf(spw[49+k], spmax[q], acc);
        }
    }
    float m = 1.0f/(1.0f+expf(-acc));
    const float* cp = ca + b * 64;
    const _Float16* fb = fp8 + (size_t)b * 8 * HWc * 8;
    _Float16* ob = outm + (size_t)b * 8 * HWc * 8;
    for (int g = 0; g < 8; g++) {
        half8 v = *(const half8*)&fb[((size_t)g * HWc + p) * 8];
        half8 hv;
        #pragma unroll
        for (int k = 0; k < 8; k++)
            hv[k] = (_Float16)((float)v[k] * cp[g * 8 + k] * m);
        *(half8*)&ob[((size_t)g * HWc + p) * 8] = hv;
    }
}

// ---------------------------------------------------------------------------
extern "C" void kernel_launch(void* const* d_in, const int* in_sizes, int n_in,
                              void* d_out, int out_size, void* d_ws, size_t ws_size,
                              hipStream_t stream)
{
    const float* x         = (const float*)d_in[0];
    const float* conv_in_w = (const float*)d_in[1];
    const float* bn1_g = (const float*)d_in[2];
    const float* bn1_b = (const float*)d_in[3];
    const float* bn1_m = (const float*)d_in[4];
    const float* bn1_v = (const float*)d_in[5];
    const float* down1_w = (const float*)d_in[6];
    const float* down1_b = (const float*)d_in[7];
    const float* down2_w = (const float*)d_in[8];
    const float* down2_b = (const float*)d_in[9];
    const float* wt_w = (const float*)d_in[10];
    const float* wt_b = (const float*)d_in[11];
    const float* edge_w = (const float*)d_in[12];
    const float* edge_b = (const float*)d_in[13];
    const float* up_w = (const float*)d_in[14];
    const float* bn2_g = (const float*)d_in[15];
    const float* bn2_b = (const float*)d_in[16];
    const float* bn2_m = (const float*)d_in[17];
    const float* bn2_v = (const float*)d_in[18];
    const float* combine_w = (const float*)d_in[19];
    const float* combine_b = (const float*)d_in[20];
    const float* fc1 = (const float*)d_in[21];
    const float* fc2 = (const float*)d_in[22];
    const float* spw = (const float*)d_in[23];
    const float* out_w = (const float*)d_in[24];
    const float* bn3_g = (const float*)d_in[25];
    const float* bn3_b = (const float*)d_in[26];
    const float* bn3_m = (const float*)d_in[27];
    const float* bn3_v = (const float*)d_in[28];
    float* out = (float*)d_out;
    float* ws = (float*)d_ws;

    // fp32 scratch
    float* z       = ws;                   // 2359296
    float* z1      = z + 2359296;
    float* xin     = z1 + 2359296;         // 262144
    float* cA      = xin + 262144;
    float* Ebuf    = cA + 262144;
    float* wtgab   = Ebuf + 262144;        // 524288
    float* spmean  = wtgab + 524288;
    float* spmaxb  = spmean + 262144;
    float* sabuf   = spmaxb + 262144;      // (unused; kept for layout)
    float* pavg    = sabuf + 262144;       // 1024
    float* pmaxb   = pavg + 1024;
    float* cab     = pmaxb + 1024;
    // f16 pack8 tensors (each 16*8*16384*8 = 16777216 f16)
    _Float16* xp      = (_Float16*)(cab + 1024);
    _Float16* x1p     = xp + 16777216;
    _Float16* f1p     = x1p + 16777216;
    _Float16* fp      = f1p + 16777216;
    // f16 weight fragments
    _Float16* wf_in   = fp + 16777216;     // 36864
    _Float16* wf_out  = wf_in + 36864;
    _Float16* wf_comb = wf_out + 36864;    // 73728
    // buffer reuse: emod overlays xp (dead after first conv64);
    //               fmod overlays f1p (dead after combine).
    _Float16* emod = xp;
    _Float16* fmod = f1p;

    prep_all_kernel<<<576, 256, 0, stream>>>(conv_in_w, out_w, combine_w,
                                             wf_in, wf_out, wf_comb);
    pack8_kernel<<<1024, 256, 0, stream>>>(x, xp);

    dim3 cgrid(256, 16);   // 4x16 tiles, 1-wave blocks
    // x1 = relu(bn1(conv_in(x)))
    mfma_conv64_kernel<<<cgrid, 64, 0, stream>>>(xp, wf_in, bn1_g,bn1_b,bn1_m,bn1_v,
                                                 x1p, nullptr);
    zmaps_kernel<<<1024, 256, 0, stream>>>(x1p, down2_w, down1_w, z, z1);
    xin_kernel<<<1024, 256, 0, stream>>>(z1, down1_b, xin);
    dwt_kernel<<<1024, 256, 0, stream>>>(z, down2_b, cA, Ebuf);
    wtgab_kernel<<<1024, 256, 0, stream>>>(cA, xin, wt_w, wt_b, wtgab);
    conv3x3_bn_kernel<<<dim3(64,16), 256, 0, stream>>>(wtgab, up_w, bn2_g,bn2_b,bn2_m,bn2_v, f1p, 2);
    // edge*(x1+1) precompute (xp is dead -> emod)
    edgemul_kernel<<<1024, 256, 0, stream>>>(Ebuf, x1p, edge_w, edge_b, emod);
    mfma_combine_kernel<<<cgrid, 64, 0, stream>>>(f1p, emod, wf_comb, combine_b, fp);
    pool_kernel<<<128, 256, 0, stream>>>(fp, pavg, pmaxb);
    mlp_kernel<<<16, 64, 0, stream>>>(pavg, pmaxb, fc1, fc2, cab);
    spstats_kernel<<<1024, 256, 0, stream>>>(fp, cab, spmean, spmaxb);
    // spatial-attn conv + fusion*ca*sa in one pass (f1p is dead -> fmod)
    spconv_modmul_kernel<<<1024, 256, 0, stream>>>(spmean, spmaxb, spw, fp, cab, fmod);
    // out = relu(bn3(conv(fmod, out_w)))
    mfma_conv64_kernel<<<cgrid, 64, 0, stream>>>(fmod, wf_out, bn3_g,bn3_b,bn3_m,bn3_v,
                                                 nullptr, out);
}

// Round 9
// 509.892 us; speedup vs baseline: 1.1161x; 1.1066x over previous
//
#include <hip/hip_runtime.h>
#include <math.h>

#define HWc 16384
#define Wd 128
#define Hd 128

typedef __attribute__((ext_vector_type(8))) _Float16 half8;
typedef __attribute__((ext_vector_type(4))) _Float16 half4;
typedef __attribute__((ext_vector_type(4))) float f32x4;

// global(16B) -> LDS DMA; lds base must be wave-uniform.
#define GLDS16(gp, lp) __builtin_amdgcn_global_load_lds( \
    (const __attribute__((address_space(1))) void*)(gp), \
    (__attribute__((address_space(3))) void*)(lp), 16, 0, 0)

// ---------------------------------------------------------------------------
// Weight fragment prep: OIHW fp32 -> f16 fragments, all three weights in one
// launch. Layout per tensor: [t(9)][kc(cin/32)][ot(4)][lane(64)][j(8)]
// ---------------------------------------------------------------------------
__global__ void prep_all_kernel(const float* __restrict__ w_in,
                                const float* __restrict__ w_out,
                                const float* __restrict__ w_comb,
                                _Float16* __restrict__ wf_in,
                                _Float16* __restrict__ wf_out,
                                _Float16* __restrict__ wf_comb)
{
    int bid = blockIdx.x;
    const float* w; _Float16* wf; int cin; int idx;
    if (bid < 144)      { w = w_in;   wf = wf_in;   cin = 64;  idx = bid * 256 + threadIdx.x; }
    else if (bid < 288) { w = w_out;  wf = wf_out;  cin = 64;  idx = (bid - 144) * 256 + threadIdx.x; }
    else                { w = w_comb; wf = wf_comb; cin = 128; idx = (bid - 288) * 256 + threadIdx.x; }
    int total = cin * 576;
    if (idx >= total) return;
    int KC = cin >> 5;
    int j = idx & 7;
    int lane = (idx >> 3) & 63;
    int rest = idx >> 9;
    int ot = rest & 3;
    int rest2 = rest >> 2;
    int kc = rest2 % KC;
    int t = rest2 / KC;
    int oc = ot * 16 + (lane & 15);
    int ci = kc * 32 + ((lane >> 4) << 3) + j;
    wf[idx] = (_Float16)w[((size_t)oc * cin + ci) * 9 + t];
}

// ---------------------------------------------------------------------------
// NCHW fp32 -> pack8 f16:  out[((b*8+g)*HW + p)*8 + k] = in[b, g*8+k, p]
// ---------------------------------------------------------------------------
__global__ __launch_bounds__(256) void pack8_kernel(const float* __restrict__ in,
                                                    _Float16* __restrict__ outp)
{
    int idx = blockIdx.x * 256 + threadIdx.x;
    int b = idx >> 14, p = idx & 16383;
    #pragma unroll
    for (int g = 0; g < 8; g++) {
        half8 v;
        #pragma unroll
        for (int k = 0; k < 8; k++)
            v[k] = (_Float16)in[((size_t)b * 64 + g * 8 + k) * HWc + p];
        *(half8*)&outp[(((size_t)b * 8 + g) * HWc + p) * 8] = v;
    }
}

// ---------------------------------------------------------------------------
// MFMA conv 64->64 3x3 (+BN+ReLU). ONE-WAVE blocks, 4x16 output tile.
// EXACT R6 body (proven 495 us config: VGPR=128, no prefetch, no spill).
// ---------------------------------------------------------------------------
__global__ __launch_bounds__(64, 4) void mfma_conv64_kernel(
    const _Float16* __restrict__ inp8, const _Float16* __restrict__ wf,
    const float* __restrict__ bng, const float* __restrict__ bnb,
    const float* __restrict__ bnm, const float* __restrict__ bnv,
    _Float16* __restrict__ outp8, float* __restrict__ out32)
{
    __shared__ __align__(16) _Float16 slds[6912];  // [g(8)][y(6)][x(18)][8]
    __shared__ float sc[64], sh[64];
    int lane = threadIdx.x;
    int b = blockIdx.y;
    int tileid = blockIdx.x;          // ty 0..31 (4-row bands), tx 0..7
    int ty = tileid >> 3, tx = tileid & 7;
    int h0 = ty * 4 - 1, w0 = tx * 16 - 1;
    {
        float inv = rsqrtf(bnv[lane] + 1e-5f);
        float s = bng[lane] * inv;
        sc[lane] = s;
        sh[lane] = bnb[lane] - bnm[lane] * s;
    }
    const _Float16* ib = inp8 + (size_t)b * 8 * HWc * 8;
    bool interior = (ty >= 1 && ty <= 30 && tx >= 1 && tx <= 6);
    if (interior) {
        #pragma unroll
        for (int it = 0; it < 14; it++) {
            int i = it * 64 + lane;
            if (i < 864) {
                int g = i / 108;
                int rem = i - g * 108;
                int y = rem / 18, x = rem - (rem / 18) * 18;
                int p = (h0 + y) * Wd + (w0 + x);
                GLDS16(&ib[((size_t)g * HWc + p) * 8], &slds[it * 512]);
            }
        }
    } else {
        // issue in-bounds DMAs; zero-fill OOB slots (disjoint addresses)
        #pragma unroll
        for (int it = 0; it < 14; it++) {
            int i = it * 64 + lane;
            if (i < 864) {
                int g = i / 108;
                int rem = i - g * 108;
                int y = rem / 18, x = rem - (rem / 18) * 18;
                int hh = h0 + y, ww = w0 + x;
                if (hh >= 0 && hh < Hd && ww >= 0 && ww < Wd) {
                    int p = hh * Wd + ww;
                    GLDS16(&ib[((size_t)g * HWc + p) * 8], &slds[it * 512]);
                } else {
                    half8 hz;
                    #pragma unroll
                    for (int k = 0; k < 8; k++) hz[k] = (_Float16)0.f;
                    *(half8*)&slds[i * 8] = hz;
                }
            }
        }
    }
    __syncthreads();   // drains DMA (vmcnt) + ds writes; single-wave: cheap
    int lq = lane >> 4, ln = lane & 15;
    f32x4 acc[4][4];
    #pragma unroll
    for (int r = 0; r < 4; r++)
        #pragma unroll
        for (int ot = 0; ot < 4; ot++)
            #pragma unroll
            for (int q = 0; q < 4; q++) acc[r][ot][q] = 0.f;

    for (int t = 0; t < 9; t++) {
        int dy = t / 3, dx = t - (t / 3) * 3;
        #pragma unroll
        for (int kc = 0; kc < 2; kc++) {
            half8 bf[4];
            #pragma unroll
            for (int r = 0; r < 4; r++) {
                int off = (((kc * 4 + lq) * 108) + (r + dy) * 18 + (ln + dx)) * 8;
                bf[r] = *(const half8*)&slds[off];
            }
            #pragma unroll
            for (int ot = 0; ot < 4; ot++) {
                half8 af = *(const half8*)(wf + (size_t)(((t * 2 + kc) * 4 + ot) * 64 + lane) * 8);
                #pragma unroll
                for (int r = 0; r < 4; r++)
                    acc[r][ot] = __builtin_amdgcn_mfma_f32_16x16x32_f16(af, bf[r], acc[r][ot], 0, 0, 0);
            }
        }
    }
    // epilogue: oc = ot*16 + lq*4 + reg = (ot*4+lq)*4 + reg
    #pragma unroll
    for (int r = 0; r < 4; r++) {
        int yy = ty * 4 + r;
        int p = yy * Wd + tx * 16 + ln;
        #pragma unroll
        for (int ot = 0; ot < 4; ot++) {
            int g4 = ot * 4 + lq;
            if (out32) {
                #pragma unroll
                for (int reg = 0; reg < 4; reg++) {
                    int oc = g4 * 4 + reg;
                    float v = fmaf(acc[r][ot][reg], sc[oc], sh[oc]);
                    out32[((size_t)b * 64 + oc) * HWc + p] = fmaxf(v, 0.f);
                }
            } else {
                half4 hv;
                #pragma unroll
                for (int reg = 0; reg < 4; reg++) {
                    int oc = g4 * 4 + reg;
                    float v = fmaf(acc[r][ot][reg], sc[oc], sh[oc]);
                    hv[reg] = (_Float16)fmaxf(v, 0.f);
                }
                *(half4*)&outp8[(((size_t)b * 8 + (g4 >> 1)) * HWc + p) * 8 + (g4 & 1) * 4] = hv;
            }
        }
    }
}

// ---------------------------------------------------------------------------
// MFMA combine conv: cat([fusion1, emod]) (128 ci) -> 64 oc, +bias.
// ONE-WAVE blocks, 4x16 tile. DOUBLE-BUFFERED: both phases' DMAs issued up
// front into disjoint LDS halves; interior tiles use counted s_waitcnt
// vmcnt(14) (phase-0 ready) then vmcnt(0) (phase-1) — no barrier at all.
// Boundary tiles (masked DMAs -> count unreliable) issue both then drain
// once. Staged values + h->t->kc accumulation order verbatim from the proven
// kernel -> bit-identical. cb read directly in epilogue (no LDS, no stray
// vmem op before the counted waits).
// ---------------------------------------------------------------------------
__global__ __launch_bounds__(64, 4) void mfma_combine_kernel(
    const _Float16* __restrict__ f1p, const _Float16* __restrict__ emod,
    const _Float16* __restrict__ wf, const float* __restrict__ cb,
    _Float16* __restrict__ outp8)
{
    __shared__ __align__(16) _Float16 slds[13824];  // 2 x [g(8)][y(6)][x(18)][8]
    int lane = threadIdx.x;
    int b = blockIdx.y;
    int tileid = blockIdx.x;
    int ty = tileid >> 3, tx = tileid & 7;
    int h0 = ty * 4 - 1, w0 = tx * 16 - 1;
    int lq = lane >> 4, ln = lane & 15;
    bool interior = (ty >= 1 && ty <= 30 && tx >= 1 && tx <= 6);
    const _Float16* f1b = f1p + (size_t)b * 8 * HWc * 8;
    const _Float16* emb = emod + (size_t)b * 8 * HWc * 8;

    if (interior) {
        // phase-0 DMA group (exactly 14 vmem ops, never zero-masked)
        #pragma unroll
        for (int it = 0; it < 14; it++) {
            int i = it * 64 + lane;
            if (i < 864) {
                int g = i / 108;
                int rem = i - g * 108;
                int y = rem / 18, x = rem - (rem / 18) * 18;
                int p = (h0 + y) * Wd + (w0 + x);
                GLDS16(&f1b[((size_t)g * HWc + p) * 8], &slds[it * 512]);
            }
        }
        __builtin_amdgcn_sched_barrier(0);   // keep group order for vmcnt math
        // phase-1 DMA group (exactly 14 vmem ops)
        #pragma unroll
        for (int it = 0; it < 14; it++) {
            int i = it * 64 + lane;
            if (i < 864) {
                int g = i / 108;
                int rem = i - g * 108;
                int y = rem / 18, x = rem - (rem / 18) * 18;
                int p = (h0 + y) * Wd + (w0 + x);
                GLDS16(&emb[((size_t)g * HWc + p) * 8], &slds[6912 + it * 512]);
            }
        }
        __builtin_amdgcn_sched_barrier(0);
    } else {
        // boundary: zero-fill OOB slots + masked DMAs for BOTH halves, then
        // a single full drain below (one stall instead of R6's two).
        #pragma unroll
        for (int ph = 0; ph < 2; ph++) {
            const _Float16* src = (ph == 0) ? f1b : emb;
            int base = ph * 6912;
            #pragma unroll
            for (int it = 0; it < 14; it++) {
                int i = it * 64 + lane;
                if (i < 864) {
                    int g = i / 108;
                    int rem = i - g * 108;
                    int y = rem / 18, x = rem - (rem / 18) * 18;
                    int hh = h0 + y, ww = w0 + x;
                    if (hh >= 0 && hh < Hd && ww >= 0 && ww < Wd) {
                        int p = hh * Wd + ww;
                        GLDS16(&src[((size_t)g * HWc + p) * 8], &slds[base + it * 512]);
                    } else {
                        half8 hz;
                        #pragma unroll
                        for (int k = 0; k < 8; k++) hz[k] = (_Float16)0.f;
                        *(half8*)&slds[(base + i * 8)];
                        *(half8*)&slds[base + i * 8] = hz;
                    }
                }
            }
        }
    }

    f32x4 acc[4][4];
    #pragma unroll
    for (int r = 0; r < 4; r++)
        #pragma unroll
        for (int ot = 0; ot < 4; ot++)
            #pragma unroll
            for (int q = 0; q < 4; q++) acc[r][ot][q] = 0.f;

    #pragma unroll
    for (int h = 0; h < 2; h++) {
        if (interior) {
            if (h == 0) asm volatile("s_waitcnt vmcnt(14)" ::: "memory");
            else        asm volatile("s_waitcnt vmcnt(0)"  ::: "memory");
            __builtin_amdgcn_sched_barrier(0);
        } else if (h == 0) {
            __syncthreads();   // single-wave: drains vmcnt + lgkm once
        }
        int base = h * 6912;
        for (int t = 0; t < 9; t++) {
            int dy = t / 3, dx = t - (t / 3) * 3;
            #pragma unroll
            for (int kc = 0; kc < 2; kc++) {
                int kcg = h * 2 + kc;
                half8 bf[4];
                #pragma unroll
                for (int r = 0; r < 4; r++) {
                    int off = (base + ((kc * 4 + lq) * 108) + (r + dy) * 18 + (ln + dx)) * 8;
                    // note: base is in elements of the 108-granular layout:
                    // byte-equivalent of h*6912 elements handled below
                    bf[r] = *(const half8*)&slds[(size_t)h * 6912 * 8 / 8 * 0 + (((kc * 4 + lq) * 108) + (r + dy) * 18 + (ln + dx)) * 8 + h * 6912 * 0];
                    (void)off;
                    bf[r] = *(const half8*)&slds[h * 6912 + (((kc * 4 + lq) * 108) + (r + dy) * 18 + (ln + dx)) * 8];
                }
                #pragma unroll
                for (int ot = 0; ot < 4; ot++) {
                    half8 af = *(const half8*)(wf + (size_t)(((t * 4 + kcg) * 4 + ot) * 64 + lane) * 8);
                    #pragma unroll
                    for (int r = 0; r < 4; r++)
                        acc[r][ot] = __builtin_amdgcn_mfma_f32_16x16x32_f16(af, bf[r], acc[r][ot], 0, 0, 0);
                }
            }
        }
    }
    #pragma unroll
    for (int r = 0; r < 4; r++) {
        int yy = ty * 4 + r;
        int p = yy * Wd + tx * 16 + ln;
        #pragma unroll
        for (int ot = 0; ot < 4; ot++) {
            int g4 = ot * 4 + lq;
            half4 hv;
            #pragma unroll
            for (int reg = 0; reg < 4; reg++) {
                int oc = g4 * 4 + reg;
                hv[reg] = (_Float16)(acc[r][ot][reg] + cb[oc]);
            }
            *(half4*)&outp8[(((size_t)b * 8 + (g4 >> 1)) * HWc + p) * 8 + (g4 & 1) * 4] = hv;
        }
    }
}

// ---------------------------------------------------------------------------
// edgemul: emod[c][p] = (f16)( edgeconv(E)[c][p] * ((float)x1[c][p] + 1) )
// ---------------------------------------------------------------------------
__global__ __launch_bounds__(256) void edgemul_kernel(const float* __restrict__ E,
    const _Float16* __restrict__ x1p, const float* __restrict__ edge_w,
    const float* __restrict__ edge_b, _Float16* __restrict__ emod)
{
    __shared__ float ew[576];
    __shared__ float ebl[64];
    int tid = threadIdx.x;
    for (int i = tid; i < 576; i += 256) ew[i] = edge_w[i];
    if (tid < 64) ebl[tid] = edge_b[tid];
    __syncthreads();
    int idx = blockIdx.x * 256 + tid;
    int b = idx >> 14, p = idx & 16383;
    int i = p >> 7, j = p & 127;
    const float* ep = E + (size_t)b * HWc;
    float e[9];
    #pragma unroll
    for (int tt = 0; tt < 9; tt++) {
        int ii = i - 1 + tt / 3, jj = j - 1 + tt % 3;
        e[tt] = (ii >= 0 && ii < Hd && jj >= 0 && jj < Wd) ? ep[ii * Wd + jj] : 0.f;
    }
    const _Float16* xb = x1p + (size_t)b * 8 * HWc * 8;
    _Float16* ob = emod + (size_t)b * 8 * HWc * 8;
    for (int g = 0; g < 8; g++) {
        half8 v = *(const half8*)&xb[((size_t)g * HWc + p) * 8];
        half8 hv;
        #pragma unroll
        for (int k = 0; k < 8; k++) {
            int cc = g * 8 + k;
            float ec = ebl[cc];
            #pragma unroll
            for (int tt = 0; tt < 9; tt++) ec = fmaf(ew[cc * 9 + tt], e[tt], ec);
            float xv = (float)v[k];
            hv[k] = (_Float16)(ec * (xv + 1.0f));
        }
        *(half8*)&ob[((size_t)g * HWc + p) * 8] = hv;
    }
}

// ---------------------------------------------------------------------------
// Scalar 3x3 conv + BN + ReLU, tiny cin (up_w conv, cin=2). Output pack8 f16.
// ---------------------------------------------------------------------------
__global__ __launch_bounds__(256) void conv3x3_bn_kernel(
    const float* __restrict__ in, const float* __restrict__ wgt,
    const float* __restrict__ bng, const float* __restrict__ bnb,
    const float* __restrict__ bnm, const float* __restrict__ bnv,
    _Float16* __restrict__ outp8, int cin)
{
    __shared__ float tile[18*18];
    __shared__ float wl[576];
    __shared__ float sc[64], sh[64];
    int tid = threadIdx.x;
    int tileid = blockIdx.x; int b = blockIdx.y;
    int th = tileid >> 3, tw = tileid & 7;
    int h0 = th*16 - 1, w0 = tw*16 - 1;
    if (tid < 64) {
        float inv = rsqrtf(bnv[tid] + 1e-5f);
        float s = bng[tid]*inv;
        sc[tid] = s;
        sh[tid] = bnb[tid] - bnm[tid]*s;
    }
    float acc[64];
    #pragma unroll
    for (int i=0;i<64;i++) acc[i]=0.f;
    int py = tid>>4, px = tid&15;
    for (int ci=0; ci<cin; ci++){
        __syncthreads();
        const float* inp = in + ((size_t)b*cin + ci)*HWc;
        for (int i = tid; i < 324; i += 256) {
            int y=i/18, x=i%18; int hh=h0+y, ww=w0+x;
            tile[i] = (hh>=0&&hh<Hd&&ww>=0&&ww<Wd) ? inp[hh*Wd+ww] : 0.f;
        }
        for (int i = tid; i < 576; i += 256) {
            int oc = i/9, t = i - oc*9;
            wl[i] = wgt[((size_t)oc*cin + ci)*9 + t];
        }
        __syncthreads();
        float v[9];
        #pragma unroll
        for (int dy=0;dy<3;dy++)
            #pragma unroll
            for (int dx=0;dx<3;dx++)
                v[dy*3+dx] = tile[(py+dy)*18 + px+dx];
        #pragma unroll
        for (int oc=0;oc<64;oc++){
            float a = acc[oc];
            #pragma unroll
            for (int t=0;t<9;t++) a = fmaf(wl[oc*9+t], v[t], a);
            acc[oc]=a;
        }
    }
    int hh = h0+1+py, ww = w0+1+px;
    int p = hh*Wd + ww;
    #pragma unroll
    for (int g=0; g<8; g++){
        half8 hv;
        #pragma unroll
        for (int k=0; k<8; k++){
            int oc = g*8+k;
            float y = fmaf(acc[oc], sc[oc], sh[oc]);
            hv[k] = (_Float16)fmaxf(y, 0.f);
        }
        *(half8*)&outp8[(((size_t)b*8+g)*HWc + p)*8] = hv;
    }
}

// ---------------------------------------------------------------------------
// z maps from pack8 x1: z_t = sum_c down2_w[c,t]*x1[c] (and z1 for down1).
// ---------------------------------------------------------------------------
__global__ __launch_bounds__(256) void zmaps_kernel(const _Float16* __restrict__ x1p,
    const float* __restrict__ w2, const float* __restrict__ w1,
    float* __restrict__ z, float* __restrict__ z1)
{
    int idx = blockIdx.x*256 + threadIdx.x;
    int b = idx >> 14; int p = idx & 16383;
    const _Float16* xb = x1p + (size_t)b*8*HWc*8;
    float a2[9], a1[9];
    #pragma unroll
    for (int t=0;t<9;t++){ a2[t]=0.f; a1[t]=0.f; }
    for (int g=0; g<8; g++){
        half8 v = *(const half8*)&xb[((size_t)g*HWc + p)*8];
        #pragma unroll
        for (int k=0;k<8;k++){
            int c = g*8+k;
            float val = (float)v[k];
            #pragma unroll
            for (int t=0;t<9;t++){
                a2[t] = fmaf(w2[c*9+t], val, a2[t]);
                a1[t] = fmaf(w1[c*9+t], val, a1[t]);
            }
        }
    }
    #pragma unroll
    for (int t=0;t<9;t++){
        z [((size_t)b*9+t)*HWc + p] = a2[t];
        z1[((size_t)b*9+t)*HWc + p] = a1[t];
    }
}

// ---------------------------------------------------------------------------
// Merged xin + dwt: both verbatim bodies (disjoint outputs, same idx map).
// ---------------------------------------------------------------------------
__global__ __launch_bounds__(256) void xindwt_kernel(const float* __restrict__ z1,
    const float* __restrict__ b1p, const float* __restrict__ z,
    const float* __restrict__ b2p, float* __restrict__ xin,
    float* __restrict__ cA, float* __restrict__ Eo)
{
    int idx = blockIdx.x*256+threadIdx.x;
    int b=idx>>14; int p=idx&16383;
    {   // xin body (verbatim)
        int i=p>>7, j=p&127;
        float acc = b1p[0];
        #pragma unroll
        for (int t=0;t<9;t++){
            int ii=i+t/3-1, jj=j+t%3-1;
            if (ii>=0&&ii<Hd&&jj>=0&&jj<Wd)
                acc += z1[((size_t)b*9+t)*HWc + ii*Wd+jj];
        }
        xin[idx]=acc;
    }
    {   // dwt body (verbatim)
        int u = p >> 7, v = p & 127;
        float b2 = b2p[0];
        int rlo[4], rhi[4]; float rf[4]; bool rv[4];
        int clo[4], chi[4]; float cf[4]; bool cvv[4];
        #pragma unroll
        for (int k=0;k<4;k++){
            int r = 2*u - 1 + k;
            rv[k] = (r>=0 && r<256);
            int rr = rv[k] ? r : 0;
            float cc = ((float)rr * 127.0f) / 255.0f;
            int lo = (int)cc;
            rlo[k]=lo; rhi[k]=min(lo+1,127); rf[k]=cc-(float)lo;
            int s = 2*v - 1 + k;
            cvv[k] = (s>=0 && s<256);
            int ss = cvv[k] ? s : 0;
            float c2 = ((float)ss * 127.0f) / 255.0f;
            int lo2=(int)c2;
            clo[k]=lo2; chi[k]=min(lo2+1,127); cf[k]=c2-(float)lo2;
        }
        float Xin[4] = {b2,b2,b2,b2};
        #pragma unroll
        for (int t=0;t<9;t++){
            int dy=t/3, dx=t%3;
            const float* zp = z + ((size_t)b*9 + t)*HWc;
            #pragma unroll
            for (int e=0;e<4;e++){
                int ey=e>>1, ex=e&1;
                int k=ey+dy, l=ex+dx;
                if (rv[k] && cvv[l]){
                    const float* row0 = zp + rlo[k]*Wd;
                    const float* row1 = zp + rhi[k]*Wd;
                    float v00=row0[clo[l]], v01=row0[chi[l]];
                    float v10=row1[clo[l]], v11=row1[chi[l]];
                    float fc_=cf[l], fr_=rf[k];
                    float top = v00*(1.0f-fc_) + v01*fc_;
                    float bot = v10*(1.0f-fc_) + v11*fc_;
                    Xin[e] += top*(1.0f-fr_) + bot*fr_;
                }
            }
        }
        float a=Xin[0], bb=Xin[1], c_=Xin[2], d_=Xin[3];
        float LL=0.5f*( a+bb+c_+d_);
        float LH=0.5f*(-a-bb+c_+d_);
        float HL=0.5f*(-a+bb-c_+d_);
        float HH=0.5f*( a-bb-c_+d_);
        cA[(size_t)b*HWc + p] = LL;
        Eo[(size_t)b*HWc + p] = fabsf(LH)+fabsf(HL)+fabsf(HH);
    }
}

__global__ __launch_bounds__(256) void wtgab_kernel(const float* __restrict__ cA,
    const float* __restrict__ xin, const float* __restrict__ wtw, const float* __restrict__ wtb,
    float* __restrict__ wtgab)
{
    __shared__ float gm[49];
    int tid=threadIdx.x;
    if (tid<49){
        int ky=tid/7, kx=tid%7;
        float yy=(float)(ky-3), xx=(float)(kx-3);
        float s=0.f;
        for (int t=0;t<4;t++){
            float theta = (float)t * 0.7853981633974483f;
            float ct=cosf(theta), st=sinf(theta);
            float xt = xx*ct + yy*st;
            float yt = -xx*st + yy*ct;
            s += expf(-0.5f*(xt*xt*(1.0f/16.0f) + yt*yt*(1.0f/64.0f))) * cosf(0.6283185307179586f*xt);
        }
        gm[tid]=0.25f*s;
    }
    __syncthreads();
    int idx = blockIdx.x*256+tid;
    int b=idx>>14; int p=idx&16383;
    int i=p>>7, j=p&127;
    float wacc = wtb[0];
    #pragma unroll
    for (int t=0;t<9;t++){
        int ii=i+t/3-1, jj=j+t%3-1;
        if (ii>=0&&ii<Hd&&jj>=0&&jj<Wd)
            wacc = fmaf(wtw[t], cA[b*HWc + ii*Wd+jj], wacc);
    }
    float g=0.f;
    for (int k=0;k<49;k++){
        int ii=i+k/7-3, jj=j+k%7-3;
        if (ii>=0&&ii<Hd&&jj>=0&&jj<Wd)
            g = fmaf(gm[k], xin[b*HWc + ii*Wd+jj], g);
    }
    wtgab[((size_t)b*2)*HWc + p] = wacc;
    wtgab[((size_t)b*2+1)*HWc + p] = 1.0f/(1.0f+expf(-g));
}

// ---------------------------------------------------------------------------
// CBAM: per-(b,g8) channel pooling from pack8 fusion.
// ---------------------------------------------------------------------------
__global__ __launch_bounds__(256) void pool_kernel(const _Float16* __restrict__ fp8,
    float* __restrict__ pavg, float* __restrict__ pmax)
{
    int b = blockIdx.x >> 3, g = blockIdx.x & 7;
    int tid = threadIdx.x;
    const _Float16* p = fp8 + ((size_t)b*8 + g)*HWc*8;
    float s[8] = {0,0,0,0,0,0,0,0};
    float m[8] = {-3.4e38f,-3.4e38f,-3.4e38f,-3.4e38f,-3.4e38f,-3.4e38f,-3.4e38f,-3.4e38f};
    for (int i=tid;i<HWc;i+=256){
        half8 v = *(const half8*)&p[(size_t)i*8];
        #pragma unroll
        for (int k=0;k<8;k++){ float u=(float)v[k]; s[k]+=u; m[k]=fmaxf(m[k],u); }
    }
    __shared__ float ss[8][256], sm[8][256];
    #pragma unroll
    for (int k=0;k<8;k++){ ss[k][tid]=s[k]; sm[k][tid]=m[k]; }
    __syncthreads();
    for (int st=128; st>0; st>>=1){
        if (tid<st){
            #pragma unroll
            for (int k=0;k<8;k++){
                ss[k][tid]+=ss[k][tid+st];
                sm[k][tid]=fmaxf(sm[k][tid],sm[k][tid+st]);
            }
        }
        __syncthreads();
    }
    if (tid<8){
        pavg[b*64 + g*8 + tid] = ss[tid][0]*(1.0f/16384.0f);
        pmax[b*64 + g*8 + tid] = sm[tid][0];
    }
}

__global__ void mlp_kernel(const float* __restrict__ pavg, const float* __restrict__ pmax,
    const float* __restrict__ fc1, const float* __restrict__ fc2, float* __restrict__ ca)
{
    int b = blockIdx.x; int tid = threadIdx.x; // 64 threads
    __shared__ float hs[4];
    if (tid < 4){
        float sa_=0.f, sm_=0.f;
        for (int c=0;c<64;c++){
            float w = fc1[tid*64+c];
            sa_ = fmaf(w, pavg[b*64+c], sa_);
            sm_ = fmaf(w, pmax[b*64+c], sm_);
        }
        hs[tid] = fmaxf(sa_,0.f) + fmaxf(sm_,0.f);
    }
    __syncthreads();
    float o = 0.f;
    #pragma unroll
    for (int j=0;j<4;j++) o = fmaf(fc2[tid*4+j], hs[j], o);
    ca[b*64+tid] = 1.0f/(1.0f+expf(-o));
}

// spatial stats of fusion*ca (read-only; fusion not modified)
__global__ __launch_bounds__(256) void spstats_kernel(const _Float16* __restrict__ fp8,
    const float* __restrict__ ca, float* __restrict__ spmean, float* __restrict__ spmax)
{
    int idx = blockIdx.x*256+threadIdx.x;
    int b = idx>>14; int p = idx&16383;
    const _Float16* fb = fp8 + (size_t)b*8*HWc*8;
    const float* cp = ca + b*64;
    float s=0.f, m=-3.4e38f;
    for (int g=0; g<8; g++){
        half8 v = *(const half8*)&fb[((size_t)g*HWc + p)*8];
        #pragma unroll
        for (int k=0;k<8;k++){
            float u = (float)v[k] * cp[g*8+k];
            s += u; m = fmaxf(m, u);
        }
    }
    spmean[idx] = s*(1.0f/64.0f);
    spmax[idx] = m;
}

// ---------------------------------------------------------------------------
// spconv + modmul fused: sa computed in-register (verbatim expression), then
// fmod[c][p] = (f16)((float)fusion[c][p] * ca[b][c] * sa) (verbatim modmul).
// ---------------------------------------------------------------------------
__global__ __launch_bounds__(256) void spconv_modmul_kernel(
    const float* __restrict__ spmean, const float* __restrict__ spmax,
    const float* __restrict__ spw, const _Float16* __restrict__ fp8,
    const float* __restrict__ ca, _Float16* __restrict__ outm)
{
    int idx = blockIdx.x*256+threadIdx.x;
    int b=idx>>14; int p=idx&16383;
    int i=p>>7, j=p&127;
    float acc=0.f;
    for (int k=0;k<49;k++){
        int ky=k/7-3, kx=k%7-3;
        int ii=i+ky, jj=j+kx;
        if (ii>=0&&ii<Hd&&jj>=0&&jj<Wd){
            int q = b*HWc + ii*Wd+jj;
            acc = fmaf(spw[k],    spmean[q], acc);
            acc = fmaf(spw[49+k], spmax[q], acc);
        }
    }
    float m = 1.0f/(1.0f+expf(-acc));
    const float* cp = ca + b * 64;
    const _Float16* fb = fp8 + (size_t)b * 8 * HWc * 8;
    _Float16* ob = outm + (size_t)b * 8 * HWc * 8;
    for (int g = 0; g < 8; g++) {
        half8 v = *(const half8*)&fb[((size_t)g * HWc + p) * 8];
        half8 hv;
        #pragma unroll
        for (int k = 0; k < 8; k++)
            hv[k] = (_Float16)((float)v[k] * cp[g * 8 + k] * m);
        *(half8*)&ob[((size_t)g * HWc + p) * 8] = hv;
    }
}

// ---------------------------------------------------------------------------
extern "C" void kernel_launch(void* const* d_in, const int* in_sizes, int n_in,
                              void* d_out, int out_size, void* d_ws, size_t ws_size,
                              hipStream_t stream)
{
    const float* x         = (const float*)d_in[0];
    const float* conv_in_w = (const float*)d_in[1];
    const float* bn1_g = (const float*)d_in[2];
    const float* bn1_b = (const float*)d_in[3];
    const float* bn1_m = (const float*)d_in[4];
    const float* bn1_v = (const float*)d_in[5];
    const float* down1_w = (const float*)d_in[6];
    const float* down1_b = (const float*)d_in[7];
    const float* down2_w = (const float*)d_in[8];
    const float* down2_b = (const float*)d_in[9];
    const float* wt_w = (const float*)d_in[10];
    const float* wt_b = (const float*)d_in[11];
    const float* edge_w = (const float*)d_in[12];
    const float* edge_b = (const float*)d_in[13];
    const float* up_w = (const float*)d_in[14];
    const float* bn2_g = (const float*)d_in[15];
    const float* bn2_b = (const float*)d_in[16];
    const float* bn2_m = (const float*)d_in[17];
    const float* bn2_v = (const float*)d_in[18];
    const float* combine_w = (const float*)d_in[19];
    const float* combine_b = (const float*)d_in[20];
    const float* fc1 = (const float*)d_in[21];
    const float* fc2 = (const float*)d_in[22];
    const float* spw = (const float*)d_in[23];
    const float* out_w = (const float*)d_in[24];
    const float* bn3_g = (const float*)d_in[25];
    const float* bn3_b = (const float*)d_in[26];
    const float* bn3_m = (const float*)d_in[27];
    const float* bn3_v = (const float*)d_in[28];
    float* out = (float*)d_out;
    float* ws = (float*)d_ws;

    // fp32 scratch
    float* z       = ws;                   // 2359296
    float* z1      = z + 2359296;
    float* xin     = z1 + 2359296;         // 262144
    float* cA      = xin + 262144;
    float* Ebuf    = cA + 262144;
    float* wtgab   = Ebuf + 262144;        // 524288
    float* spmean  = wtgab + 524288;
    float* spmaxb  = spmean + 262144;
    float* sabuf   = spmaxb + 262144;      // (unused; kept for layout)
    float* pavg    = sabuf + 262144;       // 1024
    float* pmaxb   = pavg + 1024;
    float* cab     = pmaxb + 1024;
    // f16 pack8 tensors (each 16*8*16384*8 = 16777216 f16)
    _Float16* xp      = (_Float16*)(cab + 1024);
    _Float16* x1p     = xp + 16777216;
    _Float16* f1p     = x1p + 16777216;
    _Float16* fp      = f1p + 16777216;
    // f16 weight fragments
    _Float16* wf_in   = fp + 16777216;     // 36864
    _Float16* wf_out  = wf_in + 36864;
    _Float16* wf_comb = wf_out + 36864;    // 73728
    // buffer reuse: emod overlays xp (dead after first conv64);
    //               fmod overlays f1p (dead after combine).
    _Float16* emod = xp;
    _Float16* fmod = f1p;

    prep_all_kernel<<<576, 256, 0, stream>>>(conv_in_w, out_w, combine_w,
                                             wf_in, wf_out, wf_comb);
    pack8_kernel<<<1024, 256, 0, stream>>>(x, xp);

    dim3 cgrid(256, 16);   // 4x16 tiles, 1-wave blocks
    // x1 = relu(bn1(conv_in(x)))
    mfma_conv64_kernel<<<cgrid, 64, 0, stream>>>(xp, wf_in, bn1_g,bn1_b,bn1_m,bn1_v,
                                                 x1p, nullptr);
    zmaps_kernel<<<1024, 256, 0, stream>>>(x1p, down2_w, down1_w, z, z1);
    xindwt_kernel<<<1024, 256, 0, stream>>>(z1, down1_b, z, down2_b, xin, cA, Ebuf);
    wtgab_kernel<<<1024, 256, 0, stream>>>(cA, xin, wt_w, wt_b, wtgab);
    conv3x3_bn_kernel<<<dim3(64,16), 256, 0, stream>>>(wtgab, up_w, bn2_g,bn2_b,bn2_m,bn2_v, f1p, 2);
    // edge*(x1+1) precompute (xp is dead -> emod)
    edgemul_kernel<<<1024, 256, 0, stream>>>(Ebuf, x1p, edge_w, edge_b, emod);
    mfma_combine_kernel<<<cgrid, 64, 0, stream>>>(f1p, emod, wf_comb, combine_b, fp);
    pool_kernel<<<128, 256, 0, stream>>>(fp, pavg, pmaxb);
    mlp_kernel<<<16, 64, 0, stream>>>(pavg, pmaxb, fc1, fc2, cab);
    spstats_kernel<<<1024, 256, 0, stream>>>(fp, cab, spmean, spmaxb);
    // spatial-attn conv + fusion*ca*sa in one pass (f1p is dead -> fmod)
    spconv_modmul_kernel<<<1024, 256, 0, stream>>>(spmean, spmaxb, spw, fp, cab, fmod);
    // out = relu(bn3(conv(fmod, out_w)))
    mfma_conv64_kernel<<<cgrid, 64, 0, stream>>>(fmod, wf_out, bn3_g,bn3_b,bn3_m,bn3_v,
                                                 nullptr, out);
}

// Round 12
// 483.962 us; speedup vs baseline: 1.1759x; 1.0536x over previous
//
#include <hip/hip_runtime.h>
#include <math.h>

#define HWc 16384
#define Wd 128
#define Hd 128

typedef __attribute__((ext_vector_type(8))) _Float16 half8;
typedef __attribute__((ext_vector_type(4))) _Float16 half4;
typedef __attribute__((ext_vector_type(4))) float f32x4;

// global(16B) -> LDS DMA; lds base must be wave-uniform.
#define GLDS16(gp, lp) __builtin_amdgcn_global_load_lds( \
    (const __attribute__((address_space(1))) void*)(gp), \
    (__attribute__((address_space(3))) void*)(lp), 16, 0, 0)

// ---------------------------------------------------------------------------
// Weight fragment prep: OIHW fp32 -> f16 fragments, all three weights in one
// launch (R6-proven). Layout per tensor: [t(9)][kc(cin/32)][ot(4)][lane(64)][j(8)]
// ---------------------------------------------------------------------------
__global__ void prep_all_kernel(const float* __restrict__ w_in,
                                const float* __restrict__ w_out,
                                const float* __restrict__ w_comb,
                                _Float16* __restrict__ wf_in,
                                _Float16* __restrict__ wf_out,
                                _Float16* __restrict__ wf_comb)
{
    int bid = blockIdx.x;
    const float* w; _Float16* wf; int cin; int idx;
    if (bid < 144)      { w = w_in;   wf = wf_in;   cin = 64;  idx = bid * 256 + threadIdx.x; }
    else if (bid < 288) { w = w_out;  wf = wf_out;  cin = 64;  idx = (bid - 144) * 256 + threadIdx.x; }
    else                { w = w_comb; wf = wf_comb; cin = 128; idx = (bid - 288) * 256 + threadIdx.x; }
    int total = cin * 576;
    if (idx >= total) return;
    int KC = cin >> 5;
    int j = idx & 7;
    int lane = (idx >> 3) & 63;
    int rest = idx >> 9;
    int ot = rest & 3;
    int rest2 = rest >> 2;
    int kc = rest2 % KC;
    int t = rest2 / KC;
    int oc = ot * 16 + (lane & 15);
    int ci = kc * 32 + ((lane >> 4) << 3) + j;
    wf[idx] = (_Float16)w[((size_t)oc * cin + ci) * 9 + t];
}

// ---------------------------------------------------------------------------
// NCHW fp32 -> pack8 f16:  out[((b*8+g)*HW + p)*8 + k] = in[b, g*8+k, p]
// ---------------------------------------------------------------------------
__global__ __launch_bounds__(256) void pack8_kernel(const float* __restrict__ in,
                                                    _Float16* __restrict__ outp)
{
    int idx = blockIdx.x * 256 + threadIdx.x;
    int b = idx >> 14, p = idx & 16383;
    #pragma unroll
    for (int g = 0; g < 8; g++) {
        half8 v;
        #pragma unroll
        for (int k = 0; k < 8; k++)
            v[k] = (_Float16)in[((size_t)b * 64 + g * 8 + k) * HWc + p];
        *(half8*)&outp[(((size_t)b * 8 + g) * HWc + p) * 8] = v;
    }
}

// ---------------------------------------------------------------------------
// MFMA conv 64->64 3x3 (+BN+ReLU). ONE-WAVE blocks, 4x16 output tile.
// EXACT R6 body (proven 495 us config: VGPR=128, no prefetch, no spill).
// ---------------------------------------------------------------------------
__global__ __launch_bounds__(64, 4) void mfma_conv64_kernel(
    const _Float16* __restrict__ inp8, const _Float16* __restrict__ wf,
    const float* __restrict__ bng, const float* __restrict__ bnb,
    const float* __restrict__ bnm, const float* __restrict__ bnv,
    _Float16* __restrict__ outp8, float* __restrict__ out32)
{
    __shared__ __align__(16) _Float16 slds[6912];  // [g(8)][y(6)][x(18)][8]
    __shared__ float sc[64], sh[64];
    int lane = threadIdx.x;
    int b = blockIdx.y;
    int tileid = blockIdx.x;          // ty 0..31 (4-row bands), tx 0..7
    int ty = tileid >> 3, tx = tileid & 7;
    int h0 = ty * 4 - 1, w0 = tx * 16 - 1;
    {
        float inv = rsqrtf(bnv[lane] + 1e-5f);
        float s = bng[lane] * inv;
        sc[lane] = s;
        sh[lane] = bnb[lane] - bnm[lane] * s;
    }
    const _Float16* ib = inp8 + (size_t)b * 8 * HWc * 8;
    bool interior = (ty >= 1 && ty <= 30 && tx >= 1 && tx <= 6);
    if (interior) {
        #pragma unroll
        for (int it = 0; it < 14; it++) {
            int i = it * 64 + lane;
            if (i < 864) {
                int g = i / 108;
                int rem = i - g * 108;
                int y = rem / 18, x = rem - (rem / 18) * 18;
                int p = (h0 + y) * Wd + (w0 + x);
                GLDS16(&ib[((size_t)g * HWc + p) * 8], &slds[it * 512]);
            }
        }
    } else {
        // issue in-bounds DMAs; zero-fill OOB slots (disjoint addresses)
        #pragma unroll
        for (int it = 0; it < 14; it++) {
            int i = it * 64 + lane;
            if (i < 864) {
                int g = i / 108;
                int rem = i - g * 108;
                int y = rem / 18, x = rem - (rem / 18) * 18;
                int hh = h0 + y, ww = w0 + x;
                if (hh >= 0 && hh < Hd && ww >= 0 && ww < Wd) {
                    int p = hh * Wd + ww;
                    GLDS16(&ib[((size_t)g * HWc + p) * 8], &slds[it * 512]);
                } else {
                    half8 hz;
                    #pragma unroll
                    for (int k = 0; k < 8; k++) hz[k] = (_Float16)0.f;
                    *(half8*)&slds[i * 8] = hz;
                }
            }
        }
    }
    __syncthreads();   // drains DMA (vmcnt) + ds writes; single-wave: cheap
    int lq = lane >> 4, ln = lane & 15;
    f32x4 acc[4][4];
    #pragma unroll
    for (int r = 0; r < 4; r++)
        #pragma unroll
        for (int ot = 0; ot < 4; ot++)
            #pragma unroll
            for (int q = 0; q < 4; q++) acc[r][ot][q] = 0.f;

    for (int t = 0; t < 9; t++) {
        int dy = t / 3, dx = t - (t / 3) * 3;
        #pragma unroll
        for (int kc = 0; kc < 2; kc++) {
            half8 bf[4];
            #pragma unroll
            for (int r = 0; r < 4; r++) {
                int off = (((kc * 4 + lq) * 108) + (r + dy) * 18 + (ln + dx)) * 8;
                bf[r] = *(const half8*)&slds[off];
            }
            #pragma unroll
            for (int ot = 0; ot < 4; ot++) {
                half8 af = *(const half8*)(wf + (size_t)(((t * 2 + kc) * 4 + ot) * 64 + lane) * 8);
                #pragma unroll
                for (int r = 0; r < 4; r++)
                    acc[r][ot] = __builtin_amdgcn_mfma_f32_16x16x32_f16(af, bf[r], acc[r][ot], 0, 0, 0);
            }
        }
    }
    // epilogue: oc = ot*16 + lq*4 + reg = (ot*4+lq)*4 + reg
    #pragma unroll
    for (int r = 0; r < 4; r++) {
        int yy = ty * 4 + r;
        int p = yy * Wd + tx * 16 + ln;
        #pragma unroll
        for (int ot = 0; ot < 4; ot++) {
            int g4 = ot * 4 + lq;
            if (out32) {
                #pragma unroll
                for (int reg = 0; reg < 4; reg++) {
                    int oc = g4 * 4 + reg;
                    float v = fmaf(acc[r][ot][reg], sc[oc], sh[oc]);
                    out32[((size_t)b * 64 + oc) * HWc + p] = fmaxf(v, 0.f);
                }
            } else {
                half4 hv;
                #pragma unroll
                for (int reg = 0; reg < 4; reg++) {
                    int oc = g4 * 4 + reg;
                    float v = fmaf(acc[r][ot][reg], sc[oc], sh[oc]);
                    hv[reg] = (_Float16)fmaxf(v, 0.f);
                }
                *(half4*)&outp8[(((size_t)b * 8 + (g4 >> 1)) * HWc + p) * 8 + (g4 & 1) * 4] = hv;
            }
        }
    }
}

// ---------------------------------------------------------------------------
// MFMA combine conv: cat([fusion1, emod]) (128 ci) -> 64 oc, +bias.
// EXACT R6 body (proven 65 us config): ONE-WAVE blocks, 4x16 tile,
// 2 single-buffered DMA phases, launch_bounds(64,4).
// ---------------------------------------------------------------------------
__global__ __launch_bounds__(64, 4) void mfma_combine_kernel(
    const _Float16* __restrict__ f1p, const _Float16* __restrict__ emod,
    const _Float16* __restrict__ wf, const float* __restrict__ cb,
    _Float16* __restrict__ outp8)
{
    __shared__ __align__(16) _Float16 slds[6912];
    __shared__ float cbl[64];
    int lane = threadIdx.x;
    int b = blockIdx.y;
    int tileid = blockIdx.x;
    int ty = tileid >> 3, tx = tileid & 7;
    int h0 = ty * 4 - 1, w0 = tx * 16 - 1;
    cbl[lane] = cb[lane];
    int lq = lane >> 4, ln = lane & 15;
    bool interior = (ty >= 1 && ty <= 30 && tx >= 1 && tx <= 6);
    f32x4 acc[4][4];
    #pragma unroll
    for (int r = 0; r < 4; r++)
        #pragma unroll
        for (int ot = 0; ot < 4; ot++)
            #pragma unroll
            for (int q = 0; q < 4; q++) acc[r][ot][q] = 0.f;

    const _Float16* f1b = f1p + (size_t)b * 8 * HWc * 8;
    const _Float16* emb = emod + (size_t)b * 8 * HWc * 8;
    for (int h = 0; h < 2; h++) {
        const _Float16* src = (h == 0) ? f1b : emb;
        if (h) __syncthreads();  // phase-0 reads done before overwrite
        if (interior) {
            #pragma unroll
            for (int it = 0; it < 14; it++) {
                int i = it * 64 + lane;
                if (i < 864) {
                    int g = i / 108;
                    int rem = i - g * 108;
                    int y = rem / 18, x = rem - (rem / 18) * 18;
                    int p = (h0 + y) * Wd + (w0 + x);
                    GLDS16(&src[((size_t)g * HWc + p) * 8], &slds[it * 512]);
                }
            }
        } else {
            #pragma unroll
            for (int it = 0; it < 14; it++) {
                int i = it * 64 + lane;
                if (i < 864) {
                    int g = i / 108;
                    int rem = i - g * 108;
                    int y = rem / 18, x = rem - (rem / 18) * 18;
                    int hh = h0 + y, ww = w0 + x;
                    if (hh >= 0 && hh < Hd && ww >= 0 && ww < Wd) {
                        int p = hh * Wd + ww;
                        GLDS16(&src[((size_t)g * HWc + p) * 8], &slds[it * 512]);
                    } else {
                        half8 hz;
                        #pragma unroll
                        for (int k = 0; k < 8; k++) hz[k] = (_Float16)0.f;
                        *(half8*)&slds[i * 8] = hz;
                    }
                }
            }
        }
        __syncthreads();
        for (int t = 0; t < 9; t++) {
            int dy = t / 3, dx = t - (t / 3) * 3;
            #pragma unroll
            for (int kc = 0; kc < 2; kc++) {
                int kcg = h * 2 + kc;
                half8 bf[4];
                #pragma unroll
                for (int r = 0; r < 4; r++) {
                    int off = (((kc * 4 + lq) * 108) + (r + dy) * 18 + (ln + dx)) * 8;
                    bf[r] = *(const half8*)&slds[off];
                }
                #pragma unroll
                for (int ot = 0; ot < 4; ot++) {
                    half8 af = *(const half8*)(wf + (size_t)(((t * 4 + kcg) * 4 + ot) * 64 + lane) * 8);
                    #pragma unroll
                    for (int r = 0; r < 4; r++)
                        acc[r][ot] = __builtin_amdgcn_mfma_f32_16x16x32_f16(af, bf[r], acc[r][ot], 0, 0, 0);
                }
            }
        }
    }
    #pragma unroll
    for (int r = 0; r < 4; r++) {
        int yy = ty * 4 + r;
        int p = yy * Wd + tx * 16 + ln;
        #pragma unroll
        for (int ot = 0; ot < 4; ot++) {
            int g4 = ot * 4 + lq;
            half4 hv;
            #pragma unroll
            for (int reg = 0; reg < 4; reg++) {
                int oc = g4 * 4 + reg;
                hv[reg] = (_Float16)(acc[r][ot][reg] + cbl[oc]);
            }
            *(half4*)&outp8[(((size_t)b * 8 + (g4 >> 1)) * HWc + p) * 8 + (g4 & 1) * 4] = hv;
        }
    }
}

// ---------------------------------------------------------------------------
// edgemul: emod[c][p] = (f16)( edgeconv(E)[c][p] * ((float)x1[c][p] + 1) )
// ---------------------------------------------------------------------------
__global__ __launch_bounds__(256) void edgemul_kernel(const float* __restrict__ E,
    const _Float16* __restrict__ x1p, const float* __restrict__ edge_w,
    const float* __restrict__ edge_b, _Float16* __restrict__ emod)
{
    __shared__ float ew[576];
    __shared__ float ebl[64];
    int tid = threadIdx.x;
    for (int i = tid; i < 576; i += 256) ew[i] = edge_w[i];
    if (tid < 64) ebl[tid] = edge_b[tid];
    __syncthreads();
    int idx = blockIdx.x * 256 + tid;
    int b = idx >> 14, p = idx & 16383;
    int i = p >> 7, j = p & 127;
    const float* ep = E + (size_t)b * HWc;
    float e[9];
    #pragma unroll
    for (int tt = 0; tt < 9; tt++) {
        int ii = i - 1 + tt / 3, jj = j - 1 + tt % 3;
        e[tt] = (ii >= 0 && ii < Hd && jj >= 0 && jj < Wd) ? ep[ii * Wd + jj] : 0.f;
    }
    const _Float16* xb = x1p + (size_t)b * 8 * HWc * 8;
    _Float16* ob = emod + (size_t)b * 8 * HWc * 8;
    for (int g = 0; g < 8; g++) {
        half8 v = *(const half8*)&xb[((size_t)g * HWc + p) * 8];
        half8 hv;
        #pragma unroll
        for (int k = 0; k < 8; k++) {
            int cc = g * 8 + k;
            float ec = ebl[cc];
            #pragma unroll
            for (int tt = 0; tt < 9; tt++) ec = fmaf(ew[cc * 9 + tt], e[tt], ec);
            float xv = (float)v[k];
            hv[k] = (_Float16)(ec * (xv + 1.0f));
        }
        *(half8*)&ob[((size_t)g * HWc + p) * 8] = hv;
    }
}

// ---------------------------------------------------------------------------
// Scalar 3x3 conv + BN + ReLU, tiny cin (up_w conv, cin=2). Output pack8 f16.
// ---------------------------------------------------------------------------
__global__ __launch_bounds__(256) void conv3x3_bn_kernel(
    const float* __restrict__ in, const float* __restrict__ wgt,
    const float* __restrict__ bng, const float* __restrict__ bnb,
    const float* __restrict__ bnm, const float* __restrict__ bnv,
    _Float16* __restrict__ outp8, int cin)
{
    __shared__ float tile[18*18];
    __shared__ float wl[576];
    __shared__ float sc[64], sh[64];
    int tid = threadIdx.x;
    int tileid = blockIdx.x; int b = blockIdx.y;
    int th = tileid >> 3, tw = tileid & 7;
    int h0 = th*16 - 1, w0 = tw*16 - 1;
    if (tid < 64) {
        float inv = rsqrtf(bnv[tid] + 1e-5f);
        float s = bng[tid]*inv;
        sc[tid] = s;
        sh[tid] = bnb[tid] - bnm[tid]*s;
    }
    float acc[64];
    #pragma unroll
    for (int i=0;i<64;i++) acc[i]=0.f;
    int py = tid>>4, px = tid&15;
    for (int ci=0; ci<cin; ci++){
        __syncthreads();
        const float* inp = in + ((size_t)b*cin + ci)*HWc;
        for (int i = tid; i < 324; i += 256) {
            int y=i/18, x=i%18; int hh=h0+y, ww=w0+x;
            tile[i] = (hh>=0&&hh<Hd&&ww>=0&&ww<Wd) ? inp[hh*Wd+ww] : 0.f;
        }
        for (int i = tid; i < 576; i += 256) {
            int oc = i/9, t = i - oc*9;
            wl[i] = wgt[((size_t)oc*cin + ci)*9 + t];
        }
        __syncthreads();
        float v[9];
        #pragma unroll
        for (int dy=0;dy<3;dy++)
            #pragma unroll
            for (int dx=0;dx<3;dx++)
                v[dy*3+dx] = tile[(py+dy)*18 + px+dx];
        #pragma unroll
        for (int oc=0;oc<64;oc++){
            float a = acc[oc];
            #pragma unroll
            for (int t=0;t<9;t++) a = fmaf(wl[oc*9+t], v[t], a);
            acc[oc]=a;
        }
    }
    int hh = h0+1+py, ww = w0+1+px;
    int p = hh*Wd + ww;
    #pragma unroll
    for (int g=0; g<8; g++){
        half8 hv;
        #pragma unroll
        for (int k=0; k<8; k++){
            int oc = g*8+k;
            float y = fmaf(acc[oc], sc[oc], sh[oc]);
            hv[k] = (_Float16)fmaxf(y, 0.f);
        }
        *(half8*)&outp8[(((size_t)b*8+g)*HWc + p)*8] = hv;
    }
}

// ---------------------------------------------------------------------------
// z maps from pack8 x1: z_t = sum_c down2_w[c,t]*x1[c] (and z1 for down1).
// ---------------------------------------------------------------------------
__global__ __launch_bounds__(256) void zmaps_kernel(const _Float16* __restrict__ x1p,
    const float* __restrict__ w2, const float* __restrict__ w1,
    float* __restrict__ z, float* __restrict__ z1)
{
    int idx = blockIdx.x*256 + threadIdx.x;
    int b = idx >> 14; int p = idx & 16383;
    const _Float16* xb = x1p + (size_t)b*8*HWc*8;
    float a2[9], a1[9];
    #pragma unroll
    for (int t=0;t<9;t++){ a2[t]=0.f; a1[t]=0.f; }
    for (int g=0; g<8; g++){
        half8 v = *(const half8*)&xb[((size_t)g*HWc + p)*8];
        #pragma unroll
        for (int k=0;k<8;k++){
            int c = g*8+k;
            float val = (float)v[k];
            #pragma unroll
            for (int t=0;t<9;t++){
                a2[t] = fmaf(w2[c*9+t], val, a2[t]);
                a1[t] = fmaf(w1[c*9+t], val, a1[t]);
            }
        }
    }
    #pragma unroll
    for (int t=0;t<9;t++){
        z [((size_t)b*9+t)*HWc + p] = a2[t];
        z1[((size_t)b*9+t)*HWc + p] = a1[t];
    }
}

// ---------------------------------------------------------------------------
// Merged xin + dwt: both verbatim bodies (disjoint outputs, same idx map).
// R9-proven fusion.
// ---------------------------------------------------------------------------
__global__ __launch_bounds__(256) void xindwt_kernel(const float* __restrict__ z1,
    const float* __restrict__ b1p, const float* __restrict__ z,
    const float* __restrict__ b2p, float* __restrict__ xin,
    float* __restrict__ cA, float* __restrict__ Eo)
{
    int idx = blockIdx.x*256+threadIdx.x;
    int b=idx>>14; int p=idx&16383;
    {   // xin body (verbatim)
        int i=p>>7, j=p&127;
        float acc = b1p[0];
        #pragma unroll
        for (int t=0;t<9;t++){
            int ii=i+t/3-1, jj=j+t%3-1;
            if (ii>=0&&ii<Hd&&jj>=0&&jj<Wd)
                acc += z1[((size_t)b*9+t)*HWc + ii*Wd+jj];
        }
        xin[idx]=acc;
    }
    {   // dwt body (verbatim)
        int u = p >> 7, v = p & 127;
        float b2 = b2p[0];
        int rlo[4], rhi[4]; float rf[4]; bool rv[4];
        int clo[4], chi[4]; float cf[4]; bool cvv[4];
        #pragma unroll
        for (int k=0;k<4;k++){
            int r = 2*u - 1 + k;
            rv[k] = (r>=0 && r<256);
            int rr = rv[k] ? r : 0;
            float cc = ((float)rr * 127.0f) / 255.0f;
            int lo = (int)cc;
            rlo[k]=lo; rhi[k]=min(lo+1,127); rf[k]=cc-(float)lo;
            int s = 2*v - 1 + k;
            cvv[k] = (s>=0 && s<256);
            int ss = cvv[k] ? s : 0;
            float c2 = ((float)ss * 127.0f) / 255.0f;
            int lo2=(int)c2;
            clo[k]=lo2; chi[k]=min(lo2+1,127); cf[k]=c2-(float)lo2;
        }
        float Xin[4] = {b2,b2,b2,b2};
        #pragma unroll
        for (int t=0;t<9;t++){
            int dy=t/3, dx=t%3;
            const float* zp = z + ((size_t)b*9 + t)*HWc;
            #pragma unroll
            for (int e=0;e<4;e++){
                int ey=e>>1, ex=e&1;
                int k=ey+dy, l=ex+dx;
                if (rv[k] && cvv[l]){
                    const float* row0 = zp + rlo[k]*Wd;
                    const float* row1 = zp + rhi[k]*Wd;
                    float v00=row0[clo[l]], v01=row0[chi[l]];
                    float v10=row1[clo[l]], v11=row1[chi[l]];
                    float fc_=cf[l], fr_=rf[k];
                    float top = v00*(1.0f-fc_) + v01*fc_;
                    float bot = v10*(1.0f-fc_) + v11*fc_;
                    Xin[e] += top*(1.0f-fr_) + bot*fr_;
                }
            }
        }
        float a=Xin[0], bb=Xin[1], c_=Xin[2], d_=Xin[3];
        float LL=0.5f*( a+bb+c_+d_);
        float LH=0.5f*(-a-bb+c_+d_);
        float HL=0.5f*(-a+bb-c_+d_);
        float HH=0.5f*( a-bb-c_+d_);
        cA[(size_t)b*HWc + p] = LL;
        Eo[(size_t)b*HWc + p] = fabsf(LH)+fabsf(HL)+fabsf(HH);
    }
}

__global__ __launch_bounds__(256) void wtgab_kernel(const float* __restrict__ cA,
    const float* __restrict__ xin, const float* __restrict__ wtw, const float* __restrict__ wtb,
    float* __restrict__ wtgab)
{
    __shared__ float gm[49];
    int tid=threadIdx.x;
    if (tid<49){
        int ky=tid/7, kx=tid%7;
        float yy=(float)(ky-3), xx=(float)(kx-3);
        float s=0.f;
        for (int t=0;t<4;t++){
            float theta = (float)t * 0.7853981633974483f;
            float ct=cosf(theta), st=sinf(theta);
            float xt = xx*ct + yy*st;
            float yt = -xx*st + yy*ct;
            s += expf(-0.5f*(xt*xt*(1.0f/16.0f) + yt*yt*(1.0f/64.0f))) * cosf(0.6283185307179586f*xt);
        }
        gm[tid]=0.25f*s;
    }
    __syncthreads();
    int idx = blockIdx.x*256+tid;
    int b=idx>>14; int p=idx&16383;
    int i=p>>7, j=p&127;
    float wacc = wtb[0];
    #pragma unroll
    for (int t=0;t<9;t++){
        int ii=i+t/3-1, jj=j+t%3-1;
        if (ii>=0&&ii<Hd&&jj>=0&&jj<Wd)
            wacc = fmaf(wtw[t], cA[b*HWc + ii*Wd+jj], wacc);
    }
    float g=0.f;
    for (int k=0;k<49;k++){
        int ii=i+k/7-3, jj=j+k%7-3;
        if (ii>=0&&ii<Hd&&jj>=0&&jj<Wd)
            g = fmaf(gm[k], xin[b*HWc + ii*Wd+jj], g);
    }
    wtgab[((size_t)b*2)*HWc + p] = wacc;
    wtgab[((size_t)b*2+1)*HWc + p] = 1.0f/(1.0f+expf(-g));
}

// ---------------------------------------------------------------------------
// CBAM: per-(b,g8) channel pooling from pack8 fusion.
// ---------------------------------------------------------------------------
__global__ __launch_bounds__(256) void pool_kernel(const _Float16* __restrict__ fp8,
    float* __restrict__ pavg, float* __restrict__ pmax)
{
    int b = blockIdx.x >> 3, g = blockIdx.x & 7;
    int tid = threadIdx.x;
    const _Float16* p = fp8 + ((size_t)b*8 + g)*HWc*8;
    float s[8] = {0,0,0,0,0,0,0,0};
    float m[8] = {-3.4e38f,-3.4e38f,-3.4e38f,-3.4e38f,-3.4e38f,-3.4e38f,-3.4e38f,-3.4e38f};
    for (int i=tid;i<HWc;i+=256){
        half8 v = *(const half8*)&p[(size_t)i*8];
        #pragma unroll
        for (int k=0;k<8;k++){ float u=(float)v[k]; s[k]+=u; m[k]=fmaxf(m[k],u); }
    }
    __shared__ float ss[8][256], sm[8][256];
    #pragma unroll
    for (int k=0;k<8;k++){ ss[k][tid]=s[k]; sm[k][tid]=m[k]; }
    __syncthreads();
    for (int st=128; st>0; st>>=1){
        if (tid<st){
            #pragma unroll
            for (int k=0;k<8;k++){
                ss[k][tid]+=ss[k][tid+st];
                sm[k][tid]=fmaxf(sm[k][tid],sm[k][tid+st]);
            }
        }
        __syncthreads();
    }
    if (tid<8){
        pavg[b*64 + g*8 + tid] = ss[tid][0]*(1.0f/16384.0f);
        pmax[b*64 + g*8 + tid] = sm[tid][0];
    }
}

__global__ void mlp_kernel(const float* __restrict__ pavg, const float* __restrict__ pmax,
    const float* __restrict__ fc1, const float* __restrict__ fc2, float* __restrict__ ca)
{
    int b = blockIdx.x; int tid = threadIdx.x; // 64 threads
    __shared__ float hs[4];
    if (tid < 4){
        float sa_=0.f, sm_=0.f;
        for (int c=0;c<64;c++){
            float w = fc1[tid*64+c];
            sa_ = fmaf(w, pavg[b*64+c], sa_);
            sm_ = fmaf(w, pmax[b*64+c], sm_);
        }
        hs[tid] = fmaxf(sa_,0.f) + fmaxf(sm_,0.f);
    }
    __syncthreads();
    float o = 0.f;
    #pragma unroll
    for (int j=0;j<4;j++) o = fmaf(fc2[tid*4+j], hs[j], o);
    ca[b*64+tid] = 1.0f/(1.0f+expf(-o));
}

// spatial stats of fusion*ca (read-only; fusion not modified)
__global__ __launch_bounds__(256) void spstats_kernel(const _Float16* __restrict__ fp8,
    const float* __restrict__ ca, float* __restrict__ spmean, float* __restrict__ spmax)
{
    int idx = blockIdx.x*256+threadIdx.x;
    int b = idx>>14; int p = idx&16383;
    const _Float16* fb = fp8 + (size_t)b*8*HWc*8;
    const float* cp = ca + b*64;
    float s=0.f, m=-3.4e38f;
    for (int g=0; g<8; g++){
        half8 v = *(const half8*)&fb[((size_t)g*HWc + p)*8];
        #pragma unroll
        for (int k=0;k<8;k++){
            float u = (float)v[k] * cp[g*8+k];
            s += u; m = fmaxf(m, u);
        }
    }
    spmean[idx] = s*(1.0f/64.0f);
    spmax[idx] = m;
}

// ---------------------------------------------------------------------------
// spconv + modmul fused: sa computed in-register (verbatim expression), then
// fmod[c][p] = (f16)((float)fusion[c][p] * ca[b][c] * sa) (verbatim modmul).
// ---------------------------------------------------------------------------
__global__ __launch_bounds__(256) void spconv_modmul_kernel(
    const float* __restrict__ spmean, const float* __restrict__ spmax,
    const float* __restrict__ spw, const _Float16* __restrict__ fp8,
    const float* __restrict__ ca, _Float16* __restrict__ outm)
{
    int idx = blockIdx.x*256+threadIdx.x;
    int b=idx>>14; int p=idx&16383;
    int i=p>>7, j=p&127;
    float acc=0.f;
    for (int k=0;k<49;k++){
        int ky=k/7-3, kx=k%7-3;
        int ii=i+ky, jj=j+kx;
        if (ii>=0&&ii<Hd&&jj>=0&&jj<Wd){
            int q = b*HWc + ii*Wd+jj;
            acc = fmaf(spw[k],    spmean[q], acc);
            acc = fmaf(spw[49+k], spmax[q], acc);
        }
    }
    float m = 1.0f/(1.0f+expf(-acc));
    const float* cp = ca + b * 64;
    const _Float16* fb = fp8 + (size_t)b * 8 * HWc * 8;
    _Float16* ob = outm + (size_t)b * 8 * HWc * 8;
    for (int g = 0; g < 8; g++) {
        half8 v = *(const half8*)&fb[((size_t)g * HWc + p) * 8];
        half8 hv;
        #pragma unroll
        for (int k = 0; k < 8; k++)
            hv[k] = (_Float16)((float)v[k] * cp[g * 8 + k] * m);
        *(half8*)&ob[((size_t)g * HWc + p) * 8] = hv;
    }
}

// ---------------------------------------------------------------------------
extern "C" void kernel_launch(void* const* d_in, const int* in_sizes, int n_in,
                              void* d_out, int out_size, void* d_ws, size_t ws_size,
                              hipStream_t stream)
{
    const float* x         = (const float*)d_in[0];
    const float* conv_in_w = (const float*)d_in[1];
    const float* bn1_g = (const float*)d_in[2];
    const float* bn1_b = (const float*)d_in[3];
    const float* bn1_m = (const float*)d_in[4];
    const float* bn1_v = (const float*)d_in[5];
    const float* down1_w = (const float*)d_in[6];
    const float* down1_b = (const float*)d_in[7];
    const float* down2_w = (const float*)d_in[8];
    const float* down2_b = (const float*)d_in[9];
    const float* wt_w = (const float*)d_in[10];
    const float* wt_b = (const float*)d_in[11];
    const float* edge_w = (const float*)d_in[12];
    const float* edge_b = (const float*)d_in[13];
    const float* up_w = (const float*)d_in[14];
    const float* bn2_g = (const float*)d_in[15];
    const float* bn2_b = (const float*)d_in[16];
    const float* bn2_m = (const float*)d_in[17];
    const float* bn2_v = (const float*)d_in[18];
    const float* combine_w = (const float*)d_in[19];
    const float* combine_b = (const float*)d_in[20];
    const float* fc1 = (const float*)d_in[21];
    const float* fc2 = (const float*)d_in[22];
    const float* spw = (const float*)d_in[23];
    const float* out_w = (const float*)d_in[24];
    const float* bn3_g = (const float*)d_in[25];
    const float* bn3_b = (const float*)d_in[26];
    const float* bn3_m = (const float*)d_in[27];
    const float* bn3_v = (const float*)d_in[28];
    float* out = (float*)d_out;
    float* ws = (float*)d_ws;

    // fp32 scratch
    float* z       = ws;                   // 2359296
    float* z1      = z + 2359296;
    float* xin     = z1 + 2359296;         // 262144
    float* cA      = xin + 262144;
    float* Ebuf    = cA + 262144;
    float* wtgab   = Ebuf + 262144;        // 524288
    float* spmean  = wtgab + 524288;
    float* spmaxb  = spmean + 262144;
    float* sabuf   = spmaxb + 262144;      // (unused; kept for layout)
    float* pavg    = sabuf + 262144;       // 1024
    float* pmaxb   = pavg + 1024;
    float* cab     = pmaxb + 1024;
    // f16 pack8 tensors (each 16*8*16384*8 = 16777216 f16)
    _Float16* xp      = (_Float16*)(cab + 1024);
    _Float16* x1p     = xp + 16777216;
    _Float16* f1p     = x1p + 16777216;
    _Float16* fp      = f1p + 16777216;
    // f16 weight fragments
    _Float16* wf_in   = fp + 16777216;     // 36864
    _Float16* wf_out  = wf_in + 36864;
    _Float16* wf_comb = wf_out + 36864;    // 73728
    // buffer reuse: emod overlays xp (dead after first conv64);
    //               fmod overlays f1p (dead after combine).
    _Float16* emod = xp;
    _Float16* fmod = f1p;

    prep_all_kernel<<<576, 256, 0, stream>>>(conv_in_w, out_w, combine_w,
                                             wf_in, wf_out, wf_comb);
    pack8_kernel<<<1024, 256, 0, stream>>>(x, xp);

    dim3 cgrid(256, 16);   // 4x16 tiles, 1-wave blocks
    // x1 = relu(bn1(conv_in(x)))
    mfma_conv64_kernel<<<cgrid, 64, 0, stream>>>(xp, wf_in, bn1_g,bn1_b,bn1_m,bn1_v,
                                                 x1p, nullptr);
    zmaps_kernel<<<1024, 256, 0, stream>>>(x1p, down2_w, down1_w, z, z1);
    xindwt_kernel<<<1024, 256, 0, stream>>>(z1, down1_b, z, down2_b, xin, cA, Ebuf);
    wtgab_kernel<<<1024, 256, 0, stream>>>(cA, xin, wt_w, wt_b, wtgab);
    conv3x3_bn_kernel<<<dim3(64,16), 256, 0, stream>>>(wtgab, up_w, bn2_g,bn2_b,bn2_m,bn2_v, f1p, 2);
    // edge*(x1+1) precompute (xp is dead -> emod)
    edgemul_kernel<<<1024, 256, 0, stream>>>(Ebuf, x1p, edge_w, edge_b, emod);
    mfma_combine_kernel<<<cgrid, 64, 0, stream>>>(f1p, emod, wf_comb, combine_b, fp);
    pool_kernel<<<128, 256, 0, stream>>>(fp, pavg, pmaxb);
    mlp_kernel<<<16, 64, 0, stream>>>(pavg, pmaxb, fc1, fc2, cab);
    spstats_kernel<<<1024, 256, 0, stream>>>(fp, cab, spmean, spmaxb);
    // spatial-attn conv + fusion*ca*sa in one pass (f1p is dead -> fmod)
    spconv_modmul_kernel<<<1024, 256, 0, stream>>>(spmean, spmaxb, spw, fp, cab, fmod);
    // out = relu(bn3(conv(fmod, out_w)))
    mfma_conv64_kernel<<<cgrid, 64, 0, stream>>>(fmod, wf_out, bn3_g,bn3_b,bn3_m,bn3_v,
                                                 nullptr, out);
}